// Round 11
// baseline (306.359 us; speedup 1.0000x reference)
//
#include <hip/hip_runtime.h>
#include <hip/hip_bf16.h>
#include <hip/hip_fp16.h>
#include <cstdint>
#include <cstddef>

// P=32, B=64, L=128, E=64, HB=128, HP=128, G=384, N=P*B=2048, PE=256, LH=128, NC=10

#define DINLINE __device__ __forceinline__

typedef _Float16 f16;
typedef f16 f16x8 __attribute__((ext_vector_type(8)));
typedef float f32x4 __attribute__((ext_vector_type(4)));

#define HS 136  // padded LDS row stride (f16 elements): 272B = 68 dwords = 4 mod 32 banks

static DINLINE float fast_sigmoid(float x) {
    const float e = __builtin_amdgcn_exp2f(-1.44269504089f * x);
    return __builtin_amdgcn_rcpf(1.0f + e);
}
static DINLINE float fast_tanh(float x) {
    const float e = __builtin_amdgcn_exp2f(2.88539008178f * x);
    return 1.0f - 2.0f * __builtin_amdgcn_rcpf(1.0f + e);
}

// LDS-only barrier: ds ops ordered, global stores stay in flight (no vmcnt drain)
static DINLINE void lds_barrier() {
    asm volatile("s_waitcnt lgkmcnt(0)\n\ts_barrier" ::: "memory");
    __builtin_amdgcn_sched_barrier(0);
}

// ---------------------------------------------------------------------------
// K0a: byte tables (float4 {xr+bhh_r, xz+bhh_z, xn, 0}) + ba_w1 f16 swizzle prep.
// grid 640: bx<512 tables (v=bx&255, dir=bx>>8); bx>=512 w1 col. block 384.
__global__ void k_tables_w1(const float* __restrict__ emb,
                            const float* __restrict__ wihF, const float* __restrict__ bihF,
                            const float* __restrict__ bhhF,
                            const float* __restrict__ wihB, const float* __restrict__ bihB,
                            const float* __restrict__ bhhB,
                            float4* __restrict__ tab4F, float4* __restrict__ tab4B,
                            const float* __restrict__ w1, f16* __restrict__ w1h) {
    if (blockIdx.x >= 512) {
        const int col = blockIdx.x - 512;  // 0..127
        const int k = threadIdx.x;
        if (k < 256)
            w1h[col * 256 + (k ^ ((col & 7) << 3))] = (f16)w1[col * 256 + k];
        return;
    }
    const int v = blockIdx.x & 255;
    const int dir = blockIdx.x >> 8;
    const float* wih = dir ? wihB : wihF;
    const float* bih = dir ? bihB : bihF;
    const float* bhh = dir ? bhhB : bhhF;
    float4* tab4 = dir ? tab4B : tab4F;
    __shared__ float er[64];
    __shared__ float sh[384];
    if (threadIdx.x < 64) er[threadIdx.x] = emb[v * 64 + threadIdx.x];
    __syncthreads();
    const int g = threadIdx.x;  // 384 threads
    float acc = bih[g] + (g < 256 ? bhh[g] : 0.0f);
    #pragma unroll
    for (int e = 0; e < 64; ++e) acc = fmaf(wih[g * 64 + e], er[e], acc);
    sh[g] = acc;
    __syncthreads();
    if (g < 128) {
        float4 pk;
        pk.x = sh[g];
        pk.y = sh[g + 128];
        pk.z = sh[g + 256];
        pk.w = 0.f;
        tab4[v * 128 + g] = pk;
    }
}

// ---------------------------------------------------------------------------
// K0b: transposes (2 matrices). out[c*R + r] = in[r*C + c]
struct TransArgs {
    const float* src[2];
    float* dst[2];
    int R[2];
    int C[2];
};
__global__ void k_transpose(TransArgs a) {
    const int m = blockIdx.y;
    const float* __restrict__ s = a.src[m];
    float* __restrict__ d = a.dst[m];
    const int R = a.R[m], C = a.C[m];
    const int total = R * C;
    for (int idx = blockIdx.x * blockDim.x + threadIdx.x; idx < total;
         idx += gridDim.x * blockDim.x) {
        const int r = idx / C, c = idx - r * C;
        d[c * R + r] = s[idx];
    }
}

// ---------------------------------------------------------------------------
// K2: byte BiGRU via MFMA f16. 16 rows/block, grid 256. Padded-stride LDS
// (no XOR swizzle): conflict-even banks + invariant-base addressing.
__global__ __launch_bounds__(512, 1) void k_byte_gru(
    const int* __restrict__ flow,
    const float4* __restrict__ tab4F, const float4* __restrict__ tab4B,
    const float* __restrict__ whhF, const float* __restrict__ whhB,
    const float* __restrict__ bhhF, const float* __restrict__ bhhB,
    __half* __restrict__ hF, __half* __restrict__ hB) {
    const int dir = blockIdx.x & 1;
    const int chunk = blockIdx.x >> 1;  // 0..127
    const int row0 = chunk * 16;
    const int tid = threadIdx.x;
    const int wid = tid >> 6;
    const int lane = tid & 63;
    const int c = lane & 15;
    const int q = lane >> 4;
    const int j = wid * 16 + c;  // h-col this lane produces

    const char* __restrict__ t4 =
        reinterpret_cast<const char*>(dir ? tab4B : tab4F);
    const float* __restrict__ whh = dir ? whhB : whhF;
    const float* __restrict__ bhh = dir ? bhhB : bhhF;
    __half* __restrict__ hout = dir ? hB : hF;

    __shared__ f16 hbuf[2][16 * HS];   // padded stride, no swizzle
    __shared__ int flow_lds[16][128];  // pre-scaled byte offsets v*2048

    for (int i = tid; i < 16 * 128; i += 512)
        flow_lds[i >> 7][i & 127] = (flow[row0 * 128 + i] & 255) << 11;
    {
        f16* hb = reinterpret_cast<f16*>(hbuf);
        for (int i = tid; i < 2 * 16 * HS; i += 512) hb[i] = (f16)0.f;
    }

    // B fragments: B[k][col] = whh[(g*128+j)][k]; lane: col=lane&15, k=(lane>>4)*8+e+ks*32
    f16x8 Bf[3][4];
    #pragma unroll
    for (int g = 0; g < 3; ++g) {
        #pragma unroll
        for (int ks = 0; ks < 4; ++ks) {
            const float* src = whh + (size_t)(g * 128 + j) * 128 + ks * 32 + q * 8;
            f16x8 b;
            #pragma unroll
            for (int e = 0; e < 8; ++e) b[e] = (f16)src[e];
            Bf[g][ks] = b;
        }
    }
    const float bh2 = bhh[j + 256];  // r,z biases folded into tab4
    float hold[4];
    #pragma unroll
    for (int rr = 0; rr < 4; ++rr) hold[rr] = 0.f;

    // loop-invariant address bases
    const char* t4j = t4 + (j << 4);          // + j*16B
    const int abase = c * HS + q * 8;         // A-frag element base
    const int wbase = (q * 4) * HS + j;       // gate-write base (+ rr*HS imm)
    const int srow = tid >> 5;                // store-stage row
    const int sidx = srow * HS + (tid & 31) * 4;
    __syncthreads();

    for (int t = 0; t < 128; ++t) {
        const int curb = t & 1, nxtb = curb ^ 1;
        const int tt = dir ? (127 - t) : t;

        // xg gathers (issued before the MFMA-dependent chain)
        float4 x4[4];
        #pragma unroll
        for (int rr = 0; rr < 4; ++rr)
            x4[rr] = *reinterpret_cast<const float4*>(
                t4j + flow_lds[q * 4 + rr][tt]);

        // A fragments (row = c, k = ks*32 + q*8 + e; imm offsets)
        f16x8 Af[4];
        #pragma unroll
        for (int ks = 0; ks < 4; ++ks)
            Af[ks] = *reinterpret_cast<const f16x8*>(&hbuf[curb][abase + ks * 32]);

        f32x4 a0 = {0.f, 0.f, 0.f, 0.f};
        f32x4 a1 = {0.f, 0.f, 0.f, 0.f};
        f32x4 a2 = {0.f, 0.f, 0.f, 0.f};
        #pragma unroll
        for (int ks = 0; ks < 4; ++ks) {
            a0 = __builtin_amdgcn_mfma_f32_16x16x32_f16(Af[ks], Bf[0][ks], a0, 0, 0, 0);
            a1 = __builtin_amdgcn_mfma_f32_16x16x32_f16(Af[ks], Bf[1][ks], a1, 0, 0, 0);
            a2 = __builtin_amdgcn_mfma_f32_16x16x32_f16(Af[ks], Bf[2][ks], a2, 0, 0, 0);
        }

        #pragma unroll
        for (int rr = 0; rr < 4; ++rr) {
            const float rg = fast_sigmoid(x4[rr].x + a0[rr]);
            const float zg = fast_sigmoid(x4[rr].y + a1[rr]);
            const float ng = fast_tanh(x4[rr].z + rg * (a2[rr] + bh2));
            const float hn = fmaf(zg, hold[rr] - ng, ng);
            hold[rr] = hn;
            hbuf[nxtb][wbase + rr * HS] = (f16)hn;
        }
        lds_barrier();

        // coalesced global store from hbuf[nxtb]; never drained on step path
        {
            const uint2 v = *reinterpret_cast<const uint2*>(&hbuf[nxtb][sidx]);
            *reinterpret_cast<uint2*>(
                &hout[((size_t)tt * 2048 + row0 + srow) * 128 + (tid & 31) * 4]) = v;
        }
    }
}

// ---------------------------------------------------------------------------
// K3: byte attention scores + softmax fused. grid 512 (512 positions each),
// block 256 (4 waves). W1 staged from pre-converted f16 swizzled buffer.
__global__ __launch_bounds__(256, 1) void k_scores_attn(
    const __half* __restrict__ hF, const __half* __restrict__ hB,
    const f16* __restrict__ w1h,  // [128*256] f16 pre-swizzled
    const float* __restrict__ b1, const float* __restrict__ w2,
    const float* __restrict__ b2, float* __restrict__ attn) {
    __shared__ f16 w1lds[128 * 256];  // 64 KB
    __shared__ float sc[128];
    const int tid = threadIdx.x;
    {
        const uint2* src = reinterpret_cast<const uint2*>(w1h);
        uint2* dst = reinterpret_cast<uint2*>(w1lds);
        for (int i = tid; i < 8192; i += 256) dst[i] = src[i];
    }
    const int lane = tid & 63, w = tid >> 6;
    const int c = lane & 15, q = lane >> 4;

    float b1v[8], w2v[8];
    #pragma unroll
    for (int ct = 0; ct < 8; ++ct) {
        b1v[ct] = b1[ct * 16 + c];
        w2v[ct] = w2[ct * 16 + c];
    }
    const float b2v = b2[0];
    __syncthreads();

    for (int it = 0; it < 4; ++it) {
        const int pos0 = blockIdx.x * 512 + it * 128;

        f16x8 Af[2][8];
        #pragma unroll
        for (int pt = 0; pt < 2; ++pt) {
            const size_t pos = (size_t)pos0 + (w * 2 + pt) * 16 + c;
            const f16* hFp = (const f16*)(hF + pos * 128);
            const f16* hBp = (const f16*)(hB + pos * 128);
            #pragma unroll
            for (int ks = 0; ks < 4; ++ks)
                Af[pt][ks] = *reinterpret_cast<const f16x8*>(hFp + ks * 32 + q * 8);
            #pragma unroll
            for (int ks = 0; ks < 4; ++ks)
                Af[pt][4 + ks] = *reinterpret_cast<const f16x8*>(hBp + ks * 32 + q * 8);
        }

        float s[2][4] = {{0.f, 0.f, 0.f, 0.f}, {0.f, 0.f, 0.f, 0.f}};
        #pragma unroll
        for (int ct = 0; ct < 8; ++ct) {
            const int jj = ct * 16 + c;
            f16x8 Bfr[8];
            #pragma unroll
            for (int ks = 0; ks < 8; ++ks) {
                const int k = ks * 32 + q * 8;
                Bfr[ks] = *reinterpret_cast<const f16x8*>(
                    &w1lds[jj * 256 + (k ^ ((jj & 7) << 3))]);
            }
            #pragma unroll
            for (int pt = 0; pt < 2; ++pt) {
                f32x4 acc = {0.f, 0.f, 0.f, 0.f};
                #pragma unroll
                for (int ks = 0; ks < 8; ++ks)
                    acc = __builtin_amdgcn_mfma_f32_16x16x32_f16(Af[pt][ks],
                                                                 Bfr[ks], acc,
                                                                 0, 0, 0);
                #pragma unroll
                for (int rr = 0; rr < 4; ++rr)
                    s[pt][rr] += w2v[ct] * fast_tanh(acc[rr] + b1v[ct]);
            }
        }
        #pragma unroll
        for (int pt = 0; pt < 2; ++pt) {
            #pragma unroll
            for (int rr = 0; rr < 4; ++rr) {
                float v = s[pt][rr];
                v += __shfl_xor(v, 1);
                v += __shfl_xor(v, 2);
                v += __shfl_xor(v, 4);
                v += __shfl_xor(v, 8);
                if (c == 0) sc[(w * 2 + pt) * 16 + q * 4 + rr] = v + b2v;
            }
        }
        __syncthreads();
        if (tid < 128) {
            const float sv = sc[tid];
            float m = sv;
            for (int off = 32; off; off >>= 1) m = fmaxf(m, __shfl_xor(m, off));
            const float e = __expf(sv - m);
            float sum = e;
            for (int off = 32; off; off >>= 1) sum += __shfl_xor(sum, off);
            attn[pos0 + tid] = e / sum;
        }
        __syncthreads();
    }
}

// ---------------------------------------------------------------------------
// K3b+K4pre fused: packet_emb (pe in LDS, no global roundtrip) + xg pack.
// grid 256 (8 n each), block 512 (wave per n).
__global__ __launch_bounds__(512) void k_pe_xg(
    const __half* __restrict__ hF, const __half* __restrict__ hB,
    const float* __restrict__ attn,
    const float* __restrict__ wihTF, const float* __restrict__ bihF,
    const float* __restrict__ bhhF,
    const float* __restrict__ wihTB, const float* __restrict__ bihB,
    const float* __restrict__ bhhB,
    float4* __restrict__ xg4F, float4* __restrict__ xg4B) {
    const int tid = threadIdx.x;
    const int w = tid >> 6, lane = tid & 63;
    const int rbase = blockIdx.x * 8;
    const int n = rbase + w;
    __shared__ float xrow[8][256];
    __shared__ float sh[8][384];

    // phase 1: pe row n (wave per n): 32 lanes F side, 32 lanes B side
    {
        const bool isF = lane < 32;
        const int chunk = lane & 31;
        const __half* __restrict__ hsrc =
            (isF ? hF : hB) + (size_t)n * 128 + chunk * 4;
        float a0 = 0.f, a1 = 0.f, a2 = 0.f, a3 = 0.f;
        #pragma unroll 4
        for (int l = 0; l < 128; ++l) {
            const float wv = attn[l * 2048 + n];
            const uint2 u =
                *reinterpret_cast<const uint2*>(hsrc + (size_t)l * 2048 * 128);
            const f16* hv = reinterpret_cast<const f16*>(&u);
            a0 = fmaf(wv, (float)hv[0], a0);
            a1 = fmaf(wv, (float)hv[1], a1);
            a2 = fmaf(wv, (float)hv[2], a2);
            a3 = fmaf(wv, (float)hv[3], a3);
        }
        float4 o = {a0, a1, a2, a3};
        *reinterpret_cast<float4*>(&xrow[w][(isF ? 0 : 128) + chunk * 4]) = o;
    }
    __syncthreads();

    // phase 2: xg for both dirs from LDS pe
    #pragma unroll
    for (int dir = 0; dir < 2; ++dir) {
        const float* __restrict__ wihT = dir ? wihTB : wihTF;
        const float* __restrict__ bih = dir ? bihB : bihF;
        const float* __restrict__ bhh = dir ? bhhB : bhhF;
        float4* __restrict__ xg4 = dir ? xg4B : xg4F;
        if (tid < 384) {
            const int g = tid;
            const float bias = bih[g] + (g < 256 ? bhh[g] : 0.0f);
            float acc[8];
            #pragma unroll
            for (int r = 0; r < 8; ++r) acc[r] = bias;
            for (int d = 0; d < 256; ++d) {
                const float wv = wihT[d * 384 + g];
                #pragma unroll
                for (int r = 0; r < 8; ++r) acc[r] = fmaf(wv, xrow[r][d], acc[r]);
            }
            #pragma unroll
            for (int r = 0; r < 8; ++r) sh[r][g] = acc[r];
        }
        __syncthreads();
        for (int i = tid; i < 8 * 128; i += 512) {
            const int r = i >> 7, jj = i & 127;
            float4 pk;
            pk.x = sh[r][jj];
            pk.y = sh[r][jj + 128];
            pk.z = sh[r][jj + 256];
            pk.w = 0.f;
            xg4[(size_t)(rbase + r) * 128 + jj] = pk;
        }
        __syncthreads();
    }
}

// ---------------------------------------------------------------------------
// K4: packet BiGRU via MFMA f16. grid 8, block 512 (8 waves), 32 steps.
// Same padded-stride LDS treatment as byte_gru.
__global__ __launch_bounds__(512, 1) void k_pkt_gru(
    const float4* __restrict__ xg4F, const float4* __restrict__ xg4B,
    const float* __restrict__ whhF, const float* __restrict__ whhB,
    const float* __restrict__ bhhF, const float* __restrict__ bhhB,
    float* __restrict__ h2F, float* __restrict__ h2B) {
    const int dir = blockIdx.x & 1;
    const int chunk = blockIdx.x >> 1;  // 0..3
    const int row0 = chunk * 16;
    const int tid = threadIdx.x;
    const int wid = tid >> 6;
    const int lane = tid & 63;
    const int c = lane & 15;
    const int q = lane >> 4;
    const int j = wid * 16 + c;

    const float4* __restrict__ xg4 = dir ? xg4B : xg4F;
    const float* __restrict__ whh = dir ? whhB : whhF;
    const float* __restrict__ bhh = dir ? bhhB : bhhF;
    float* __restrict__ hout = dir ? h2B : h2F;

    __shared__ f16 hbuf[2][16 * HS];

    {
        f16* hb = reinterpret_cast<f16*>(hbuf);
        for (int i = tid; i < 2 * 16 * HS; i += 512) hb[i] = (f16)0.f;
    }

    f16x8 Bf[3][4];
    #pragma unroll
    for (int g = 0; g < 3; ++g) {
        #pragma unroll
        for (int ks = 0; ks < 4; ++ks) {
            const float* src = whh + (size_t)(g * 128 + j) * 128 + ks * 32 + q * 8;
            f16x8 b;
            #pragma unroll
            for (int e = 0; e < 8; ++e) b[e] = (f16)src[e];
            Bf[g][ks] = b;
        }
    }
    const float bh2 = bhh[j + 256];  // r,z biases folded into xg
    float hold[4];
    #pragma unroll
    for (int rr = 0; rr < 4; ++rr) hold[rr] = 0.f;

    const int abase = c * HS + q * 8;
    const int wbase = (q * 4) * HS + j;
    __syncthreads();

    for (int t = 0; t < 32; ++t) {
        const int curb = t & 1, nxtb = curb ^ 1;
        const int tt = dir ? (31 - t) : t;

        float4 x4[4];
        #pragma unroll
        for (int rr = 0; rr < 4; ++rr)
            x4[rr] = xg4[(size_t)(tt * 64 + row0 + q * 4 + rr) * 128 + j];

        f16x8 Af[4];
        #pragma unroll
        for (int ks = 0; ks < 4; ++ks)
            Af[ks] = *reinterpret_cast<const f16x8*>(&hbuf[curb][abase + ks * 32]);

        f32x4 a0 = {0.f, 0.f, 0.f, 0.f};
        f32x4 a1 = {0.f, 0.f, 0.f, 0.f};
        f32x4 a2 = {0.f, 0.f, 0.f, 0.f};
        #pragma unroll
        for (int ks = 0; ks < 4; ++ks) {
            a0 = __builtin_amdgcn_mfma_f32_16x16x32_f16(Af[ks], Bf[0][ks], a0, 0, 0, 0);
            a1 = __builtin_amdgcn_mfma_f32_16x16x32_f16(Af[ks], Bf[1][ks], a1, 0, 0, 0);
            a2 = __builtin_amdgcn_mfma_f32_16x16x32_f16(Af[ks], Bf[2][ks], a2, 0, 0, 0);
        }

        #pragma unroll
        for (int rr = 0; rr < 4; ++rr) {
            const float rg = fast_sigmoid(x4[rr].x + a0[rr]);
            const float zg = fast_sigmoid(x4[rr].y + a1[rr]);
            const float ng = fast_tanh(x4[rr].z + rg * (a2[rr] + bh2));
            const float hn = fmaf(zg, hold[rr] - ng, ng);
            hold[rr] = hn;
            hbuf[nxtb][wbase + rr * HS] = (f16)hn;
            hout[((size_t)tt * 64 + row0 + q * 4 + rr) * 128 + j] = hn;
        }
        lds_barrier();
    }
}

// ---------------------------------------------------------------------------
// K5a: packet attention scores. grid 2048 (n), block 128.
__global__ __launch_bounds__(128) void k_scores2(
    const float* __restrict__ h2F, const float* __restrict__ h2B,
    const float* __restrict__ paw1,  // [128][256] row-major
    const float* __restrict__ pab1, const float* __restrict__ paw2,
    const float* __restrict__ pab2, float* __restrict__ scores2) {
    const int n = blockIdx.x;
    const int tid = threadIdx.x;  // 128
    __shared__ float x[256];
    __shared__ float red[2];
    x[tid] = h2F[n * 128 + tid];
    x[tid + 128] = h2B[n * 128 + tid];
    __syncthreads();
    float acc = pab1[tid];
    const float* wr = paw1 + tid * 256;
    #pragma unroll 8
    for (int d = 0; d < 256; ++d) acc = fmaf(wr[d], x[d], acc);
    float s = paw2[tid] * fast_tanh(acc);
    s += __shfl_xor(s, 1);
    s += __shfl_xor(s, 2);
    s += __shfl_xor(s, 4);
    s += __shfl_xor(s, 8);
    s += __shfl_xor(s, 16);
    s += __shfl_xor(s, 32);
    if ((tid & 63) == 0) red[tid >> 6] = s;
    __syncthreads();
    if (tid == 0) scores2[n] = red[0] + red[1] + pab2[0];
}

// ---------------------------------------------------------------------------
// K5b: softmax over b + weighted sum + final FC. grid 32 (p), block 256.
__global__ __launch_bounds__(256) void k_final3(
    const float* __restrict__ h2F, const float* __restrict__ h2B,
    const float* __restrict__ scores2, const float* __restrict__ wf,
    const float* __restrict__ bfv, float* __restrict__ outp) {
    const int p = blockIdx.x;
    const int tid = threadIdx.x;
    __shared__ float sc[64];
    __shared__ float femb[256];
    __shared__ float red[64];

    if (tid < 64) {
        const float s = scores2[p * 64 + tid];
        float m = s;
        for (int off = 32; off; off >>= 1) m = fmaxf(m, __shfl_xor(m, off));
        const float e = __expf(s - m);
        float sum = e;
        for (int off = 32; off; off >>= 1) sum += __shfl_xor(sum, off);
        sc[tid] = e / sum;
    }
    __syncthreads();

    {
        const float* __restrict__ hsrc = (tid < 128) ? h2F : h2B;
        const int d = tid & 127;
        float acc = 0.f;
        for (int b = 0; b < 64; ++b)
            acc = fmaf(sc[b], hsrc[(p * 64 + b) * 128 + d], acc);
        femb[tid] = acc;
    }
    __syncthreads();

    const float fv = femb[tid];
    #pragma unroll
    for (int c = 0; c < 10; ++c) {
        float s = fv * wf[c * 256 + tid];
        s += __shfl_xor(s, 1);
        s += __shfl_xor(s, 2);
        s += __shfl_xor(s, 4);
        s += __shfl_xor(s, 8);
        s += __shfl_xor(s, 16);
        s += __shfl_xor(s, 32);
        if ((tid & 63) == 0) red[(c << 2) | (tid >> 6)] = s;
        __syncthreads();
        if (tid == 0)
            outp[p * 10 + c] = bfv[c] + red[c << 2] + red[(c << 2) | 1] +
                               red[(c << 2) | 2] + red[(c << 2) | 3];
        __syncthreads();
    }
}

// ---------------------------------------------------------------------------
extern "C" void kernel_launch(void* const* d_in, const int* in_sizes, int n_in,
                              void* d_out, int out_size, void* d_ws,
                              size_t ws_size, hipStream_t stream) {
    const int* flow = (const int*)d_in[0];
    const float* emb = (const float*)d_in[1];
    const float* byte_wih_f = (const float*)d_in[2];
    const float* byte_whh_f = (const float*)d_in[3];
    const float* byte_bih_f = (const float*)d_in[4];
    const float* byte_bhh_f = (const float*)d_in[5];
    const float* byte_wih_b = (const float*)d_in[6];
    const float* byte_whh_b = (const float*)d_in[7];
    const float* byte_bih_b = (const float*)d_in[8];
    const float* byte_bhh_b = (const float*)d_in[9];
    const float* pkt_wih_f = (const float*)d_in[10];
    const float* pkt_whh_f = (const float*)d_in[11];
    const float* pkt_bih_f = (const float*)d_in[12];
    const float* pkt_bhh_f = (const float*)d_in[13];
    const float* pkt_wih_b = (const float*)d_in[14];
    const float* pkt_whh_b = (const float*)d_in[15];
    const float* pkt_bih_b = (const float*)d_in[16];
    const float* pkt_bhh_b = (const float*)d_in[17];
    const float* ba_w1 = (const float*)d_in[18];
    const float* ba_b1 = (const float*)d_in[19];
    const float* ba_w2 = (const float*)d_in[20];
    const float* ba_b2 = (const float*)d_in[21];
    const float* pa_w1 = (const float*)d_in[22];
    const float* pa_b1 = (const float*)d_in[23];
    const float* pa_w2 = (const float*)d_in[24];
    const float* pa_b2 = (const float*)d_in[25];
    const float* wf = (const float*)d_in[26];
    const float* bf = (const float*)d_in[27];

    char* base = (char*)d_ws;
    size_t off = 0;
    auto allocf = [&](size_t nf) -> float* {
        float* p = (float*)(base + off);
        off += nf * sizeof(float);
        return p;
    };
    auto alloch = [&](size_t nh) -> __half* {
        off = (off + 255) & ~(size_t)255;
        __half* p = (__half*)(base + off);
        off += nh * sizeof(__half);
        return p;
    };
    float* wihTpF = allocf(256 * 384);
    float* wihTpB = allocf(256 * 384);
    float* attn = allocf(262144);
    float4* tab4F = (float4*)allocf(256 * 128 * 4);
    float4* tab4B = (float4*)allocf(256 * 128 * 4);
    float4* xg4F = (float4*)allocf((size_t)2048 * 128 * 4);
    float4* xg4B = (float4*)allocf((size_t)2048 * 128 * 4);
    float* h2F = allocf(32 * 64 * 128);
    float* h2B = allocf(32 * 64 * 128);
    float* scores2 = allocf(2048);
    __half* w1h = alloch(128 * 256);
    __half* hF = alloch((size_t)128 * 2048 * 128);
    __half* hB = alloch((size_t)128 * 2048 * 128);
    if (off > ws_size) return;  // diagnostic: leaves d_out poisoned
    (void)in_sizes; (void)n_in; (void)out_size;

    k_tables_w1<<<640, 384, 0, stream>>>(emb, byte_wih_f, byte_bih_f,
                                         byte_bhh_f, byte_wih_b, byte_bih_b,
                                         byte_bhh_b, tab4F, tab4B, ba_w1,
                                         (f16*)w1h);

    TransArgs ta;
    ta.src[0] = pkt_wih_f; ta.dst[0] = wihTpF; ta.R[0] = 384; ta.C[0] = 256;
    ta.src[1] = pkt_wih_b; ta.dst[1] = wihTpB; ta.R[1] = 384; ta.C[1] = 256;
    k_transpose<<<dim3(96, 2), 256, 0, stream>>>(ta);

    k_byte_gru<<<256, 512, 0, stream>>>(flow, tab4F, tab4B, byte_whh_f,
                                        byte_whh_b, byte_bhh_f, byte_bhh_b, hF,
                                        hB);

    k_scores_attn<<<512, 256, 0, stream>>>(hF, hB, (const f16*)w1h, ba_b1,
                                           ba_w2, ba_b2, attn);

    k_pe_xg<<<256, 512, 0, stream>>>(hF, hB, attn, wihTpF, pkt_bih_f,
                                     pkt_bhh_f, wihTpB, pkt_bih_b, pkt_bhh_b,
                                     xg4F, xg4B);

    k_pkt_gru<<<8, 512, 0, stream>>>(xg4F, xg4B, pkt_whh_f, pkt_whh_b,
                                     pkt_bhh_f, pkt_bhh_b, h2F, h2B);
    k_scores2<<<2048, 128, 0, stream>>>(h2F, h2B, pa_w1, pa_b1, pa_w2, pa_b2,
                                        scores2);
    k_final3<<<32, 256, 0, stream>>>(h2F, h2B, scores2, wf, bf, (float*)d_out);
}

// Round 12
// 287.676 us; speedup vs baseline: 1.0649x; 1.0649x over previous
//
#include <hip/hip_runtime.h>
#include <hip/hip_bf16.h>
#include <hip/hip_fp16.h>
#include <cstdint>
#include <cstddef>

// P=32, B=64, L=128, E=64, HB=128, HP=128, G=384, N=P*B=2048, PE=256, LH=128, NC=10
// Gate scaling folded into weights/tables: r,z pre-scaled by -log2(e),
// n pre-scaled by 2*log2(e)  =>  sigmoid = rcp(1+exp2(x)), tanh = 1-2*rcp(1+exp2(x)).

#define DINLINE __device__ __forceinline__

typedef _Float16 f16;
typedef f16 f16x8 __attribute__((ext_vector_type(8)));
typedef float f32x4 __attribute__((ext_vector_type(4)));

#define SCL_RZ (-1.44269504089f)
#define SCL_N (2.88539008178f)

static DINLINE float fast_tanh(float x) {  // unscaled-input version (scores2)
    const float e = __builtin_amdgcn_exp2f(2.88539008178f * x);
    return 1.0f - 2.0f * __builtin_amdgcn_rcpf(1.0f + e);
}

// LDS-only barrier: ds ops ordered, global stores stay in flight (no vmcnt drain)
static DINLINE void lds_barrier() {
    asm volatile("s_waitcnt lgkmcnt(0)\n\ts_barrier" ::: "memory");
    __builtin_amdgcn_sched_barrier(0);
}

// ---------------------------------------------------------------------------
// K0a: byte tables (float4 {scl_rz*(xr+bhh_r), scl_rz*(xz+bhh_z), scl_n*xn, 0})
// + ba_w1 f16 swizzle prep (pre-scaled by SCL_N).
// grid 640: bx<512 tables (v=bx&255, dir=bx>>8); bx>=512 w1 col. block 384.
__global__ void k_tables_w1(const float* __restrict__ emb,
                            const float* __restrict__ wihF, const float* __restrict__ bihF,
                            const float* __restrict__ bhhF,
                            const float* __restrict__ wihB, const float* __restrict__ bihB,
                            const float* __restrict__ bhhB,
                            float4* __restrict__ tab4F, float4* __restrict__ tab4B,
                            const float* __restrict__ w1, f16* __restrict__ w1h) {
    if (blockIdx.x >= 512) {
        const int col = blockIdx.x - 512;  // 0..127
        const int k = threadIdx.x;
        if (k < 256)
            w1h[col * 256 + (k ^ ((col & 7) << 3))] =
                (f16)(SCL_N * w1[col * 256 + k]);
        return;
    }
    const int v = blockIdx.x & 255;
    const int dir = blockIdx.x >> 8;
    const float* wih = dir ? wihB : wihF;
    const float* bih = dir ? bihB : bihF;
    const float* bhh = dir ? bhhB : bhhF;
    float4* tab4 = dir ? tab4B : tab4F;
    __shared__ float er[64];
    __shared__ float sh[384];
    if (threadIdx.x < 64) er[threadIdx.x] = emb[v * 64 + threadIdx.x];
    __syncthreads();
    const int g = threadIdx.x;  // 384 threads
    float acc = bih[g] + (g < 256 ? bhh[g] : 0.0f);
    #pragma unroll
    for (int e = 0; e < 64; ++e) acc = fmaf(wih[g * 64 + e], er[e], acc);
    sh[g] = acc * (g < 256 ? SCL_RZ : SCL_N);
    __syncthreads();
    if (g < 128) {
        float4 pk;
        pk.x = sh[g];
        pk.y = sh[g + 128];
        pk.z = sh[g + 256];
        pk.w = 0.f;
        tab4[v * 128 + g] = pk;
    }
}

// ---------------------------------------------------------------------------
// K0b: transposes (2 matrices). out[c*R + r] = in[r*C + c]
struct TransArgs {
    const float* src[2];
    float* dst[2];
    int R[2];
    int C[2];
};
__global__ void k_transpose(TransArgs a) {
    const int m = blockIdx.y;
    const float* __restrict__ s = a.src[m];
    float* __restrict__ d = a.dst[m];
    const int R = a.R[m], C = a.C[m];
    const int total = R * C;
    for (int idx = blockIdx.x * blockDim.x + threadIdx.x; idx < total;
         idx += gridDim.x * blockDim.x) {
        const int r = idx / C, c = idx - r * C;
        d[c * R + r] = s[idx];
    }
}

// ---------------------------------------------------------------------------
// K2: byte BiGRU via MFMA f16 (R8 structure; weights pre-scaled per gate).
__global__ __launch_bounds__(512, 1) void k_byte_gru(
    const int* __restrict__ flow,
    const float4* __restrict__ tab4F, const float4* __restrict__ tab4B,
    const float* __restrict__ whhF, const float* __restrict__ whhB,
    const float* __restrict__ bhhF, const float* __restrict__ bhhB,
    __half* __restrict__ hF, __half* __restrict__ hB) {
    const int dir = blockIdx.x & 1;
    const int chunk = blockIdx.x >> 1;  // 0..127
    const int row0 = chunk * 16;
    const int tid = threadIdx.x;
    const int wid = tid >> 6;
    const int lane = tid & 63;
    const int c = lane & 15;
    const int q = lane >> 4;
    const int j = wid * 16 + c;  // h-col this lane produces

    const float4* __restrict__ t4 = dir ? tab4B : tab4F;  // [v*128 + j]
    const float* __restrict__ whh = dir ? whhB : whhF;
    const float* __restrict__ bhh = dir ? bhhB : bhhF;
    __half* __restrict__ hout = dir ? hB : hF;

    __shared__ f16 hbuf[2][16 * 128];  // swizzled: row*128 + (k ^ ((row&7)<<3))
    __shared__ int flow_lds[16][128];

    for (int i = tid; i < 16 * 128; i += 512)
        flow_lds[i >> 7][i & 127] = flow[row0 * 128 + i] & 255;
    for (int i = tid; i < 16 * 128; i += 512) hbuf[0][i] = (f16)0.f;

    // B fragments: B[k][col] = scl(g)*whh[(g*128+j)][k]
    f16x8 Bf[3][4];
    #pragma unroll
    for (int g = 0; g < 3; ++g) {
        const float scl = (g == 2) ? SCL_N : SCL_RZ;
        #pragma unroll
        for (int ks = 0; ks < 4; ++ks) {
            const float* src = whh + (size_t)(g * 128 + j) * 128 + ks * 32 + q * 8;
            f16x8 b;
            #pragma unroll
            for (int e = 0; e < 8; ++e) b[e] = (f16)(scl * src[e]);
            Bf[g][ks] = b;
        }
    }
    const float bh2 = SCL_N * bhh[j + 256];  // r,z biases folded into tab4
    float hold[4];
    #pragma unroll
    for (int rr = 0; rr < 4; ++rr) hold[rr] = 0.f;
    __syncthreads();

    for (int t = 0; t < 128; ++t) {
        const int curb = t & 1, nxtb = curb ^ 1;
        const int tt = dir ? (127 - t) : t;

        // xg gathers (issued before the MFMA-dependent chain)
        float4 x4[4];
        #pragma unroll
        for (int rr = 0; rr < 4; ++rr)
            x4[rr] = t4[flow_lds[q * 4 + rr][tt] * 128 + j];

        // A fragments (row = c, k = ks*32 + q*8 + e, swizzled)
        f16x8 Af[4];
        #pragma unroll
        for (int ks = 0; ks < 4; ++ks) {
            const int kb = ks * 32 + q * 8;
            const int idx = c * 128 + (kb ^ ((c & 7) << 3));
            Af[ks] = *reinterpret_cast<const f16x8*>(&hbuf[curb][idx]);
        }

        f32x4 a0 = {0.f, 0.f, 0.f, 0.f};
        f32x4 a1 = {0.f, 0.f, 0.f, 0.f};
        f32x4 a2 = {0.f, 0.f, 0.f, 0.f};
        #pragma unroll
        for (int ks = 0; ks < 4; ++ks) {
            a0 = __builtin_amdgcn_mfma_f32_16x16x32_f16(Af[ks], Bf[0][ks], a0, 0, 0, 0);
            a1 = __builtin_amdgcn_mfma_f32_16x16x32_f16(Af[ks], Bf[1][ks], a1, 0, 0, 0);
            a2 = __builtin_amdgcn_mfma_f32_16x16x32_f16(Af[ks], Bf[2][ks], a2, 0, 0, 0);
        }

        #pragma unroll
        for (int rr = 0; rr < 4; ++rr) {
            // all inputs pre-scaled: sigmoid = rcp(1+exp2(.)), tanh = 1-2rcp(1+exp2(.))
            const float e0 = __builtin_amdgcn_exp2f(x4[rr].x + a0[rr]);
            const float rg = __builtin_amdgcn_rcpf(1.0f + e0);
            const float e1 = __builtin_amdgcn_exp2f(x4[rr].y + a1[rr]);
            const float zg = __builtin_amdgcn_rcpf(1.0f + e1);
            const float e2 =
                __builtin_amdgcn_exp2f(x4[rr].z + rg * (a2[rr] + bh2));
            const float ng = fmaf(-2.0f, __builtin_amdgcn_rcpf(1.0f + e2), 1.0f);
            const float hn = fmaf(zg, hold[rr] - ng, ng);
            hold[rr] = hn;
            const int row = q * 4 + rr;
            hbuf[nxtb][row * 128 + (j ^ ((row & 7) << 3))] = (f16)hn;
        }
        lds_barrier();

        // coalesced global store from hbuf[nxtb]; never drained on step path
        {
            const int row = tid >> 5;
            const int ho = (tid & 31) * 4;
            const int idx = row * 128 + (ho ^ ((row & 7) << 3));
            const uint2 v = *reinterpret_cast<const uint2*>(&hbuf[nxtb][idx]);
            *reinterpret_cast<uint2*>(
                &hout[((size_t)tt * 2048 + row0 + row) * 128 + ho]) = v;
        }
    }
}

// ---------------------------------------------------------------------------
// K3: byte attention scores + softmax fused. grid 512 (512 positions each),
// block 256 (4 waves). W1 staged from pre-converted f16 swizzled+scaled buffer.
__global__ __launch_bounds__(256, 1) void k_scores_attn(
    const __half* __restrict__ hF, const __half* __restrict__ hB,
    const f16* __restrict__ w1h,  // [128*256] f16 pre-swizzled, *SCL_N
    const float* __restrict__ b1, const float* __restrict__ w2,
    const float* __restrict__ b2, float* __restrict__ attn) {
    __shared__ f16 w1lds[128 * 256];  // 64 KB
    __shared__ float sc[128];
    const int tid = threadIdx.x;
    {
        const uint2* src = reinterpret_cast<const uint2*>(w1h);
        uint2* dst = reinterpret_cast<uint2*>(w1lds);
        for (int i = tid; i < 8192; i += 256) dst[i] = src[i];
    }
    const int lane = tid & 63, w = tid >> 6;
    const int c = lane & 15, q = lane >> 4;

    float b1v[8], w2v[8];
    #pragma unroll
    for (int ct = 0; ct < 8; ++ct) {
        b1v[ct] = SCL_N * b1[ct * 16 + c];
        w2v[ct] = w2[ct * 16 + c];
    }
    const float b2v = b2[0];
    __syncthreads();

    for (int it = 0; it < 4; ++it) {
        const int pos0 = blockIdx.x * 512 + it * 128;

        f16x8 Af[2][8];
        #pragma unroll
        for (int pt = 0; pt < 2; ++pt) {
            const size_t pos = (size_t)pos0 + (w * 2 + pt) * 16 + c;
            const f16* hFp = (const f16*)(hF + pos * 128);
            const f16* hBp = (const f16*)(hB + pos * 128);
            #pragma unroll
            for (int ks = 0; ks < 4; ++ks)
                Af[pt][ks] = *reinterpret_cast<const f16x8*>(hFp + ks * 32 + q * 8);
            #pragma unroll
            for (int ks = 0; ks < 4; ++ks)
                Af[pt][4 + ks] = *reinterpret_cast<const f16x8*>(hBp + ks * 32 + q * 8);
        }

        float s[2][4] = {{0.f, 0.f, 0.f, 0.f}, {0.f, 0.f, 0.f, 0.f}};
        #pragma unroll
        for (int ct = 0; ct < 8; ++ct) {
            const int jj = ct * 16 + c;
            f16x8 Bfr[8];
            #pragma unroll
            for (int ks = 0; ks < 8; ++ks) {
                const int k = ks * 32 + q * 8;
                Bfr[ks] = *reinterpret_cast<const f16x8*>(
                    &w1lds[jj * 256 + (k ^ ((jj & 7) << 3))]);
            }
            #pragma unroll
            for (int pt = 0; pt < 2; ++pt) {
                f32x4 acc = {0.f, 0.f, 0.f, 0.f};
                #pragma unroll
                for (int ks = 0; ks < 8; ++ks)
                    acc = __builtin_amdgcn_mfma_f32_16x16x32_f16(Af[pt][ks],
                                                                 Bfr[ks], acc,
                                                                 0, 0, 0);
                #pragma unroll
                for (int rr = 0; rr < 4; ++rr) {
                    // tanh with pre-scaled arg
                    const float e2 = __builtin_amdgcn_exp2f(acc[rr] + b1v[ct]);
                    const float th =
                        fmaf(-2.0f, __builtin_amdgcn_rcpf(1.0f + e2), 1.0f);
                    s[pt][rr] = fmaf(w2v[ct], th, s[pt][rr]);
                }
            }
        }
        #pragma unroll
        for (int pt = 0; pt < 2; ++pt) {
            #pragma unroll
            for (int rr = 0; rr < 4; ++rr) {
                float v = s[pt][rr];
                v += __shfl_xor(v, 1);
                v += __shfl_xor(v, 2);
                v += __shfl_xor(v, 4);
                v += __shfl_xor(v, 8);
                if (c == 0) sc[(w * 2 + pt) * 16 + q * 4 + rr] = v + b2v;
            }
        }
        __syncthreads();
        if (tid < 128) {
            const float sv = sc[tid];
            float m = sv;
            for (int off = 32; off; off >>= 1) m = fmaxf(m, __shfl_xor(m, off));
            const float e = __expf(sv - m);
            float sum = e;
            for (int off = 32; off; off >>= 1) sum += __shfl_xor(sum, off);
            attn[pos0 + tid] = e / sum;
        }
        __syncthreads();
    }
}

// ---------------------------------------------------------------------------
// K3b: packet_emb[n,d] = sum_l attn[l,n] * h[l,n,d]. grid 512 (4 n each),
// block 256 (R8 version).
__global__ __launch_bounds__(256) void k_packet_emb(
    const __half* __restrict__ hF, const __half* __restrict__ hB,
    const float* __restrict__ attn, float* __restrict__ pe) {
    const int tid = threadIdx.x;
    const int g = tid >> 6;          // n group
    const int lane = tid & 63;
    const int n = blockIdx.x * 4 + g;
    const bool isF = lane < 32;
    const int chunk = lane & 31;     // 4 f16 per chunk
    const __half* __restrict__ hsrc = (isF ? hF : hB) + (size_t)n * 128 + chunk * 4;
    float acc0 = 0.f, acc1 = 0.f, acc2 = 0.f, acc3 = 0.f;
    #pragma unroll 4
    for (int l = 0; l < 128; ++l) {
        const float wv = attn[l * 2048 + n];
        const uint2 u = *reinterpret_cast<const uint2*>(hsrc + (size_t)l * 2048 * 128);
        const f16* hv = reinterpret_cast<const f16*>(&u);
        acc0 = fmaf(wv, (float)hv[0], acc0);
        acc1 = fmaf(wv, (float)hv[1], acc1);
        acc2 = fmaf(wv, (float)hv[2], acc2);
        acc3 = fmaf(wv, (float)hv[3], acc3);
    }
    float4 o = {acc0, acc1, acc2, acc3};
    *reinterpret_cast<float4*>(&pe[n * 256 + (isF ? 0 : 128) + chunk * 4]) = o;
}

// ---------------------------------------------------------------------------
// K4pre: packed xg4[row*128+j] = {scl_rz*(xr+bhh_r), scl_rz*(xz+bhh_z), scl_n*xn, 0}.
// grid (256,2), block 384.
__global__ __launch_bounds__(384) void k_pkt_xg(
    const float* __restrict__ pe, const float* __restrict__ wihTF,
    const float* __restrict__ bihF, const float* __restrict__ bhhF,
    const float* __restrict__ wihTB, const float* __restrict__ bihB,
    const float* __restrict__ bhhB, float4* __restrict__ xg4F,
    float4* __restrict__ xg4B) {
    const int dir = blockIdx.y;
    const float* __restrict__ wihT = dir ? wihTB : wihTF;
    const float* __restrict__ bih = dir ? bihB : bihF;
    const float* __restrict__ bhh = dir ? bhhB : bhhF;
    float4* __restrict__ xg4 = dir ? xg4B : xg4F;
    const int rbase = blockIdx.x * 8;
    __shared__ float xrow[8][256];
    __shared__ float sh[8][384];
    for (int i = threadIdx.x; i < 8 * 256; i += 384)
        xrow[i >> 8][i & 255] = pe[rbase * 256 + i];
    __syncthreads();
    const int g = threadIdx.x;
    float acc[8];
    const float bias = bih[g] + (g < 256 ? bhh[g] : 0.0f);
    #pragma unroll
    for (int r = 0; r < 8; ++r) acc[r] = bias;
    for (int d = 0; d < 256; ++d) {
        const float w = wihT[d * 384 + g];
        #pragma unroll
        for (int r = 0; r < 8; ++r) acc[r] = fmaf(w, xrow[r][d], acc[r]);
    }
    const float scl = (g < 256) ? SCL_RZ : SCL_N;
    #pragma unroll
    for (int r = 0; r < 8; ++r) sh[r][g] = scl * acc[r];
    __syncthreads();
    for (int i = threadIdx.x; i < 8 * 128; i += 384) {
        const int r = i >> 7, jj = i & 127;
        float4 pk;
        pk.x = sh[r][jj];
        pk.y = sh[r][jj + 128];
        pk.z = sh[r][jj + 256];
        pk.w = 0.f;
        xg4[(size_t)(rbase + r) * 128 + jj] = pk;
    }
}

// ---------------------------------------------------------------------------
// K4: packet BiGRU via MFMA f16. grid 8, block 512 (8 waves), 32 steps.
__global__ __launch_bounds__(512, 1) void k_pkt_gru(
    const float4* __restrict__ xg4F, const float4* __restrict__ xg4B,
    const float* __restrict__ whhF, const float* __restrict__ whhB,
    const float* __restrict__ bhhF, const float* __restrict__ bhhB,
    float* __restrict__ h2F, float* __restrict__ h2B) {
    const int dir = blockIdx.x & 1;
    const int chunk = blockIdx.x >> 1;  // 0..3
    const int row0 = chunk * 16;
    const int tid = threadIdx.x;
    const int wid = tid >> 6;
    const int lane = tid & 63;
    const int c = lane & 15;
    const int q = lane >> 4;
    const int j = wid * 16 + c;

    const float4* __restrict__ xg4 = dir ? xg4B : xg4F;
    const float* __restrict__ whh = dir ? whhB : whhF;
    const float* __restrict__ bhh = dir ? bhhB : bhhF;
    float* __restrict__ hout = dir ? h2B : h2F;

    __shared__ f16 hbuf[2][16 * 128];

    for (int i = tid; i < 16 * 128; i += 512) hbuf[0][i] = (f16)0.f;

    f16x8 Bf[3][4];
    #pragma unroll
    for (int g = 0; g < 3; ++g) {
        const float scl = (g == 2) ? SCL_N : SCL_RZ;
        #pragma unroll
        for (int ks = 0; ks < 4; ++ks) {
            const float* src = whh + (size_t)(g * 128 + j) * 128 + ks * 32 + q * 8;
            f16x8 b;
            #pragma unroll
            for (int e = 0; e < 8; ++e) b[e] = (f16)(scl * src[e]);
            Bf[g][ks] = b;
        }
    }
    const float bh2 = SCL_N * bhh[j + 256];
    float hold[4];
    #pragma unroll
    for (int rr = 0; rr < 4; ++rr) hold[rr] = 0.f;
    __syncthreads();

    for (int t = 0; t < 32; ++t) {
        const int curb = t & 1, nxtb = curb ^ 1;
        const int tt = dir ? (31 - t) : t;

        float4 x4[4];
        #pragma unroll
        for (int rr = 0; rr < 4; ++rr)
            x4[rr] = xg4[(size_t)(tt * 64 + row0 + q * 4 + rr) * 128 + j];

        f16x8 Af[4];
        #pragma unroll
        for (int ks = 0; ks < 4; ++ks) {
            const int kb = ks * 32 + q * 8;
            const int idx = c * 128 + (kb ^ ((c & 7) << 3));
            Af[ks] = *reinterpret_cast<const f16x8*>(&hbuf[curb][idx]);
        }

        f32x4 a0 = {0.f, 0.f, 0.f, 0.f};
        f32x4 a1 = {0.f, 0.f, 0.f, 0.f};
        f32x4 a2 = {0.f, 0.f, 0.f, 0.f};
        #pragma unroll
        for (int ks = 0; ks < 4; ++ks) {
            a0 = __builtin_amdgcn_mfma_f32_16x16x32_f16(Af[ks], Bf[0][ks], a0, 0, 0, 0);
            a1 = __builtin_amdgcn_mfma_f32_16x16x32_f16(Af[ks], Bf[1][ks], a1, 0, 0, 0);
            a2 = __builtin_amdgcn_mfma_f32_16x16x32_f16(Af[ks], Bf[2][ks], a2, 0, 0, 0);
        }

        #pragma unroll
        for (int rr = 0; rr < 4; ++rr) {
            const float e0 = __builtin_amdgcn_exp2f(x4[rr].x + a0[rr]);
            const float rg = __builtin_amdgcn_rcpf(1.0f + e0);
            const float e1 = __builtin_amdgcn_exp2f(x4[rr].y + a1[rr]);
            const float zg = __builtin_amdgcn_rcpf(1.0f + e1);
            const float e2 =
                __builtin_amdgcn_exp2f(x4[rr].z + rg * (a2[rr] + bh2));
            const float ng = fmaf(-2.0f, __builtin_amdgcn_rcpf(1.0f + e2), 1.0f);
            const float hn = fmaf(zg, hold[rr] - ng, ng);
            hold[rr] = hn;
            const int row = q * 4 + rr;
            hbuf[nxtb][row * 128 + (j ^ ((row & 7) << 3))] = (f16)hn;
            hout[((size_t)tt * 64 + row0 + row) * 128 + j] = hn;
        }
        lds_barrier();
    }
}

// ---------------------------------------------------------------------------
// K5a: packet attention scores. grid 2048 (n), block 128.
__global__ __launch_bounds__(128) void k_scores2(
    const float* __restrict__ h2F, const float* __restrict__ h2B,
    const float* __restrict__ paw1,  // [128][256] row-major
    const float* __restrict__ pab1, const float* __restrict__ paw2,
    const float* __restrict__ pab2, float* __restrict__ scores2) {
    const int n = blockIdx.x;
    const int tid = threadIdx.x;  // 128
    __shared__ float x[256];
    __shared__ float red[2];
    x[tid] = h2F[n * 128 + tid];
    x[tid + 128] = h2B[n * 128 + tid];
    __syncthreads();
    float acc = pab1[tid];
    const float* wr = paw1 + tid * 256;
    #pragma unroll 8
    for (int d = 0; d < 256; ++d) acc = fmaf(wr[d], x[d], acc);
    float s = paw2[tid] * fast_tanh(acc);
    s += __shfl_xor(s, 1);
    s += __shfl_xor(s, 2);
    s += __shfl_xor(s, 4);
    s += __shfl_xor(s, 8);
    s += __shfl_xor(s, 16);
    s += __shfl_xor(s, 32);
    if ((tid & 63) == 0) red[tid >> 6] = s;
    __syncthreads();
    if (tid == 0) scores2[n] = red[0] + red[1] + pab2[0];
}

// ---------------------------------------------------------------------------
// K5b: softmax over b + weighted sum + final FC. grid 32 (p), block 256.
__global__ __launch_bounds__(256) void k_final3(
    const float* __restrict__ h2F, const float* __restrict__ h2B,
    const float* __restrict__ scores2, const float* __restrict__ wf,
    const float* __restrict__ bfv, float* __restrict__ outp) {
    const int p = blockIdx.x;
    const int tid = threadIdx.x;
    __shared__ float sc[64];
    __shared__ float femb[256];
    __shared__ float red[64];

    if (tid < 64) {
        const float s = scores2[p * 64 + tid];
        float m = s;
        for (int off = 32; off; off >>= 1) m = fmaxf(m, __shfl_xor(m, off));
        const float e = __expf(s - m);
        float sum = e;
        for (int off = 32; off; off >>= 1) sum += __shfl_xor(sum, off);
        sc[tid] = e / sum;
    }
    __syncthreads();

    {
        const float* __restrict__ hsrc = (tid < 128) ? h2F : h2B;
        const int d = tid & 127;
        float acc = 0.f;
        for (int b = 0; b < 64; ++b)
            acc = fmaf(sc[b], hsrc[(p * 64 + b) * 128 + d], acc);
        femb[tid] = acc;
    }
    __syncthreads();

    const float fv = femb[tid];
    #pragma unroll
    for (int c = 0; c < 10; ++c) {
        float s = fv * wf[c * 256 + tid];
        s += __shfl_xor(s, 1);
        s += __shfl_xor(s, 2);
        s += __shfl_xor(s, 4);
        s += __shfl_xor(s, 8);
        s += __shfl_xor(s, 16);
        s += __shfl_xor(s, 32);
        if ((tid & 63) == 0) red[(c << 2) | (tid >> 6)] = s;
        __syncthreads();
        if (tid == 0)
            outp[p * 10 + c] = bfv[c] + red[c << 2] + red[(c << 2) | 1] +
                               red[(c << 2) | 2] + red[(c << 2) | 3];
        __syncthreads();
    }
}

// ---------------------------------------------------------------------------
extern "C" void kernel_launch(void* const* d_in, const int* in_sizes, int n_in,
                              void* d_out, int out_size, void* d_ws,
                              size_t ws_size, hipStream_t stream) {
    const int* flow = (const int*)d_in[0];
    const float* emb = (const float*)d_in[1];
    const float* byte_wih_f = (const float*)d_in[2];
    const float* byte_whh_f = (const float*)d_in[3];
    const float* byte_bih_f = (const float*)d_in[4];
    const float* byte_bhh_f = (const float*)d_in[5];
    const float* byte_wih_b = (const float*)d_in[6];
    const float* byte_whh_b = (const float*)d_in[7];
    const float* byte_bih_b = (const float*)d_in[8];
    const float* byte_bhh_b = (const float*)d_in[9];
    const float* pkt_wih_f = (const float*)d_in[10];
    const float* pkt_whh_f = (const float*)d_in[11];
    const float* pkt_bih_f = (const float*)d_in[12];
    const float* pkt_bhh_f = (const float*)d_in[13];
    const float* pkt_wih_b = (const float*)d_in[14];
    const float* pkt_whh_b = (const float*)d_in[15];
    const float* pkt_bih_b = (const float*)d_in[16];
    const float* pkt_bhh_b = (const float*)d_in[17];
    const float* ba_w1 = (const float*)d_in[18];
    const float* ba_b1 = (const float*)d_in[19];
    const float* ba_w2 = (const float*)d_in[20];
    const float* ba_b2 = (const float*)d_in[21];
    const float* pa_w1 = (const float*)d_in[22];
    const float* pa_b1 = (const float*)d_in[23];
    const float* pa_w2 = (const float*)d_in[24];
    const float* pa_b2 = (const float*)d_in[25];
    const float* wf = (const float*)d_in[26];
    const float* bf = (const float*)d_in[27];

    char* base = (char*)d_ws;
    size_t off = 0;
    auto allocf = [&](size_t nf) -> float* {
        float* p = (float*)(base + off);
        off += nf * sizeof(float);
        return p;
    };
    auto alloch = [&](size_t nh) -> __half* {
        off = (off + 255) & ~(size_t)255;
        __half* p = (__half*)(base + off);
        off += nh * sizeof(__half);
        return p;
    };
    float* wihTpF = allocf(256 * 384);
    float* wihTpB = allocf(256 * 384);
    float* attn = allocf(262144);
    float* pe = allocf(2048 * 256);
    float4* tab4F = (float4*)allocf(256 * 128 * 4);
    float4* tab4B = (float4*)allocf(256 * 128 * 4);
    float4* xg4F = (float4*)allocf((size_t)2048 * 128 * 4);
    float4* xg4B = (float4*)allocf((size_t)2048 * 128 * 4);
    float* h2F = allocf(32 * 64 * 128);
    float* h2B = allocf(32 * 64 * 128);
    float* scores2 = allocf(2048);
    __half* w1h = alloch(128 * 256);
    __half* hF = alloch((size_t)128 * 2048 * 128);
    __half* hB = alloch((size_t)128 * 2048 * 128);
    if (off > ws_size) return;  // diagnostic: leaves d_out poisoned
    (void)in_sizes; (void)n_in; (void)out_size;

    k_tables_w1<<<640, 384, 0, stream>>>(emb, byte_wih_f, byte_bih_f,
                                         byte_bhh_f, byte_wih_b, byte_bih_b,
                                         byte_bhh_b, tab4F, tab4B, ba_w1,
                                         (f16*)w1h);

    TransArgs ta;
    ta.src[0] = pkt_wih_f; ta.dst[0] = wihTpF; ta.R[0] = 384; ta.C[0] = 256;
    ta.src[1] = pkt_wih_b; ta.dst[1] = wihTpB; ta.R[1] = 384; ta.C[1] = 256;
    k_transpose<<<dim3(96, 2), 256, 0, stream>>>(ta);

    k_byte_gru<<<256, 512, 0, stream>>>(flow, tab4F, tab4B, byte_whh_f,
                                        byte_whh_b, byte_bhh_f, byte_bhh_b, hF,
                                        hB);

    k_scores_attn<<<512, 256, 0, stream>>>(hF, hB, (const f16*)w1h, ba_b1,
                                           ba_w2, ba_b2, attn);
    k_packet_emb<<<512, 256, 0, stream>>>(hF, hB, attn, pe);

    k_pkt_xg<<<dim3(256, 2), 384, 0, stream>>>(pe, wihTpF, pkt_bih_f,
                                               pkt_bhh_f, wihTpB, pkt_bih_b,
                                               pkt_bhh_b, xg4F, xg4B);
    k_pkt_gru<<<8, 512, 0, stream>>>(xg4F, xg4B, pkt_whh_f, pkt_whh_b,
                                     pkt_bhh_f, pkt_bhh_b, h2F, h2B);
    k_scores2<<<2048, 128, 0, stream>>>(h2F, h2B, pa_w1, pa_b1, pa_w2, pa_b2,
                                        scores2);
    k_final3<<<32, 256, 0, stream>>>(h2F, h2B, scores2, wf, bf, (float*)d_out);
}

// Round 13
// 282.527 us; speedup vs baseline: 1.0843x; 1.0182x over previous
//
#include <hip/hip_runtime.h>
#include <hip/hip_bf16.h>
#include <hip/hip_fp16.h>
#include <cstdint>
#include <cstddef>

// P=32, B=64, L=128, E=64, HB=128, HP=128, G=384, N=P*B=2048, PE=256, LH=128, NC=10
// Gate scaling folded into weights/tables: r,z pre-scaled by -log2(e),
// n pre-scaled by 2*log2(e)  =>  sigmoid = rcp(1+exp2(x)), tanh = 1-2*rcp(1+exp2(x)).

#define DINLINE __device__ __forceinline__

typedef _Float16 f16;
typedef f16 f16x8 __attribute__((ext_vector_type(8)));
typedef float f32x4 __attribute__((ext_vector_type(4)));

#define SCL_RZ (-1.44269504089f)
#define SCL_N (2.88539008178f)

static DINLINE float fast_tanh(float x) {  // unscaled-input version (scores2)
    const float e = __builtin_amdgcn_exp2f(2.88539008178f * x);
    return 1.0f - 2.0f * __builtin_amdgcn_rcpf(1.0f + e);
}

// LDS-only barrier: ds ops ordered, global stores stay in flight (no vmcnt drain)
static DINLINE void lds_barrier() {
    asm volatile("s_waitcnt lgkmcnt(0)\n\ts_barrier" ::: "memory");
    __builtin_amdgcn_sched_barrier(0);
}

// ---------------------------------------------------------------------------
// K0: byte tables (scaled, packed float4) + ba_w1 f16 swizzle prep (scaled)
//     + pkt_wih transposes. grid 832, block 384.
__global__ void k_tables_w1(const float* __restrict__ emb,
                            const float* __restrict__ wihF, const float* __restrict__ bihF,
                            const float* __restrict__ bhhF,
                            const float* __restrict__ wihB, const float* __restrict__ bihB,
                            const float* __restrict__ bhhB,
                            float4* __restrict__ tab4F, float4* __restrict__ tab4B,
                            const float* __restrict__ w1, f16* __restrict__ w1h,
                            const float* __restrict__ pwihF, const float* __restrict__ pwihB,
                            float* __restrict__ wihTpF, float* __restrict__ wihTpB) {
    if (blockIdx.x >= 640) {  // transposes: 2 matrices x 96 blocks
        const int bid = blockIdx.x - 640;
        const int m = bid / 96, bx = bid % 96;
        const float* __restrict__ s = m ? pwihB : pwihF;
        float* __restrict__ d = m ? wihTpB : wihTpF;
        for (int idx = bx * 384 + threadIdx.x; idx < 384 * 256; idx += 96 * 384) {
            const int r = idx >> 8, c = idx & 255;
            d[c * 384 + r] = s[idx];
        }
        return;
    }
    if (blockIdx.x >= 512) {  // w1 prep
        const int col = blockIdx.x - 512;  // 0..127
        const int k = threadIdx.x;
        if (k < 256)
            w1h[col * 256 + (k ^ ((col & 7) << 3))] =
                (f16)(SCL_N * w1[col * 256 + k]);
        return;
    }
    const int v = blockIdx.x & 255;
    const int dir = blockIdx.x >> 8;
    const float* wih = dir ? wihB : wihF;
    const float* bih = dir ? bihB : bihF;
    const float* bhh = dir ? bhhB : bhhF;
    float4* tab4 = dir ? tab4B : tab4F;
    __shared__ float er[64];
    __shared__ float sh[384];
    if (threadIdx.x < 64) er[threadIdx.x] = emb[v * 64 + threadIdx.x];
    __syncthreads();
    const int g = threadIdx.x;  // 384 threads
    float acc = bih[g] + (g < 256 ? bhh[g] : 0.0f);
    #pragma unroll
    for (int e = 0; e < 64; ++e) acc = fmaf(wih[g * 64 + e], er[e], acc);
    sh[g] = acc * (g < 256 ? SCL_RZ : SCL_N);
    __syncthreads();
    if (g < 128) {
        float4 pk;
        pk.x = sh[g];
        pk.y = sh[g + 128];
        pk.z = sh[g + 256];
        pk.w = 0.f;
        tab4[v * 128 + g] = pk;
    }
}

// ---------------------------------------------------------------------------
// K2: byte BiGRU via MFMA f16. flow_lds transposed [t][row] (one b128 per
// step), direct per-lane h stores (no post-barrier LDS read-back).
__global__ __launch_bounds__(512, 1) void k_byte_gru(
    const int* __restrict__ flow,
    const float4* __restrict__ tab4F, const float4* __restrict__ tab4B,
    const float* __restrict__ whhF, const float* __restrict__ whhB,
    const float* __restrict__ bhhF, const float* __restrict__ bhhB,
    __half* __restrict__ hF, __half* __restrict__ hB) {
    const int dir = blockIdx.x & 1;
    const int chunk = blockIdx.x >> 1;  // 0..127
    const int row0 = chunk * 16;
    const int tid = threadIdx.x;
    const int wid = tid >> 6;
    const int lane = tid & 63;
    const int c = lane & 15;
    const int q = lane >> 4;
    const int j = wid * 16 + c;  // h-col this lane produces

    const char* __restrict__ t4j =
        reinterpret_cast<const char*>(dir ? tab4B : tab4F) + (j << 4);
    const float* __restrict__ whh = dir ? whhB : whhF;
    const float* __restrict__ bhh = dir ? bhhB : bhhF;
    __half* __restrict__ hout = dir ? hB : hF;

    __shared__ f16 hbuf[2][16 * 128];   // swizzled: row*128 + (k ^ ((row&7)<<3))
    __shared__ int flow_lds[128][16];   // [t][row], pre-scaled v*2048 (byte off)

    for (int i = tid; i < 16 * 128; i += 512) {
        const int row = i >> 7, t = i & 127;
        flow_lds[t][row] = (flow[row0 * 128 + i] & 255) << 11;
    }
    for (int i = tid; i < 16 * 128; i += 512) hbuf[0][i] = (f16)0.f;

    // B fragments: B[k][col] = scl(g)*whh[(g*128+j)][k]
    f16x8 Bf[3][4];
    #pragma unroll
    for (int g = 0; g < 3; ++g) {
        const float scl = (g == 2) ? SCL_N : SCL_RZ;
        #pragma unroll
        for (int ks = 0; ks < 4; ++ks) {
            const float* src = whh + (size_t)(g * 128 + j) * 128 + ks * 32 + q * 8;
            f16x8 b;
            #pragma unroll
            for (int e = 0; e < 8; ++e) b[e] = (f16)(scl * src[e]);
            Bf[g][ks] = b;
        }
    }
    const float bh2 = SCL_N * bhh[j + 256];  // r,z biases folded into tab4
    float hold[4];
    #pragma unroll
    for (int rr = 0; rr < 4; ++rr) hold[rr] = 0.f;
    __syncthreads();

    for (int t = 0; t < 128; ++t) {
        const int curb = t & 1, nxtb = curb ^ 1;
        const int tt = dir ? (127 - t) : t;

        // one b128 read: 4 rows' table byte-offsets for step tt
        const int4 off4 = *reinterpret_cast<const int4*>(&flow_lds[tt][q * 4]);
        float4 x4[4];
        x4[0] = *reinterpret_cast<const float4*>(t4j + off4.x);
        x4[1] = *reinterpret_cast<const float4*>(t4j + off4.y);
        x4[2] = *reinterpret_cast<const float4*>(t4j + off4.z);
        x4[3] = *reinterpret_cast<const float4*>(t4j + off4.w);

        // A fragments (row = c, k = ks*32 + q*8 + e, swizzled)
        f16x8 Af[4];
        #pragma unroll
        for (int ks = 0; ks < 4; ++ks) {
            const int kb = ks * 32 + q * 8;
            const int idx = c * 128 + (kb ^ ((c & 7) << 3));
            Af[ks] = *reinterpret_cast<const f16x8*>(&hbuf[curb][idx]);
        }

        f32x4 a0 = {0.f, 0.f, 0.f, 0.f};
        f32x4 a1 = {0.f, 0.f, 0.f, 0.f};
        f32x4 a2 = {0.f, 0.f, 0.f, 0.f};
        #pragma unroll
        for (int ks = 0; ks < 4; ++ks) {
            a0 = __builtin_amdgcn_mfma_f32_16x16x32_f16(Af[ks], Bf[0][ks], a0, 0, 0, 0);
            a1 = __builtin_amdgcn_mfma_f32_16x16x32_f16(Af[ks], Bf[1][ks], a1, 0, 0, 0);
            a2 = __builtin_amdgcn_mfma_f32_16x16x32_f16(Af[ks], Bf[2][ks], a2, 0, 0, 0);
        }

        __half* hp = hout + ((size_t)tt * 2048 + row0 + q * 4) * 128 + j;
        #pragma unroll
        for (int rr = 0; rr < 4; ++rr) {
            const float e0 = __builtin_amdgcn_exp2f(x4[rr].x + a0[rr]);
            const float rg = __builtin_amdgcn_rcpf(1.0f + e0);
            const float e1 = __builtin_amdgcn_exp2f(x4[rr].y + a1[rr]);
            const float zg = __builtin_amdgcn_rcpf(1.0f + e1);
            const float e2 =
                __builtin_amdgcn_exp2f(x4[rr].z + rg * (a2[rr] + bh2));
            const float ng = fmaf(-2.0f, __builtin_amdgcn_rcpf(1.0f + e2), 1.0f);
            const float hn = fmaf(zg, hold[rr] - ng, ng);
            hold[rr] = hn;
            const int row = q * 4 + rr;
            hbuf[nxtb][row * 128 + (j ^ ((row & 7) << 3))] = (f16)hn;
            hp[rr * 128] = (__half)hn;  // direct store, never drained in-loop
        }
        lds_barrier();
    }
}

// ---------------------------------------------------------------------------
// K3: byte attention scores + softmax fused. grid 1024 (256 positions each),
// block 256 (4 waves). W1 staged from pre-converted f16 swizzled+scaled buffer.
__global__ __launch_bounds__(256, 1) void k_scores_attn(
    const __half* __restrict__ hF, const __half* __restrict__ hB,
    const f16* __restrict__ w1h,  // [128*256] f16 pre-swizzled, *SCL_N
    const float* __restrict__ b1, const float* __restrict__ w2,
    const float* __restrict__ b2, float* __restrict__ attn) {
    __shared__ f16 w1lds[128 * 256];  // 64 KB
    __shared__ float sc[128];
    const int tid = threadIdx.x;
    {
        const uint2* src = reinterpret_cast<const uint2*>(w1h);
        uint2* dst = reinterpret_cast<uint2*>(w1lds);
        for (int i = tid; i < 8192; i += 256) dst[i] = src[i];
    }
    const int lane = tid & 63, w = tid >> 6;
    const int c = lane & 15, q = lane >> 4;

    float b1v[8], w2v[8];
    #pragma unroll
    for (int ct = 0; ct < 8; ++ct) {
        b1v[ct] = SCL_N * b1[ct * 16 + c];
        w2v[ct] = w2[ct * 16 + c];
    }
    const float b2v = b2[0];
    __syncthreads();

    for (int it = 0; it < 2; ++it) {
        const int pos0 = blockIdx.x * 256 + it * 128;

        f16x8 Af[2][8];
        #pragma unroll
        for (int pt = 0; pt < 2; ++pt) {
            const size_t pos = (size_t)pos0 + (w * 2 + pt) * 16 + c;
            const f16* hFp = (const f16*)(hF + pos * 128);
            const f16* hBp = (const f16*)(hB + pos * 128);
            #pragma unroll
            for (int ks = 0; ks < 4; ++ks)
                Af[pt][ks] = *reinterpret_cast<const f16x8*>(hFp + ks * 32 + q * 8);
            #pragma unroll
            for (int ks = 0; ks < 4; ++ks)
                Af[pt][4 + ks] = *reinterpret_cast<const f16x8*>(hBp + ks * 32 + q * 8);
        }

        float s[2][4] = {{0.f, 0.f, 0.f, 0.f}, {0.f, 0.f, 0.f, 0.f}};
        #pragma unroll
        for (int ct = 0; ct < 8; ++ct) {
            const int jj = ct * 16 + c;
            f16x8 Bfr[8];
            #pragma unroll
            for (int ks = 0; ks < 8; ++ks) {
                const int k = ks * 32 + q * 8;
                Bfr[ks] = *reinterpret_cast<const f16x8*>(
                    &w1lds[jj * 256 + (k ^ ((jj & 7) << 3))]);
            }
            #pragma unroll
            for (int pt = 0; pt < 2; ++pt) {
                f32x4 acc = {0.f, 0.f, 0.f, 0.f};
                #pragma unroll
                for (int ks = 0; ks < 8; ++ks)
                    acc = __builtin_amdgcn_mfma_f32_16x16x32_f16(Af[pt][ks],
                                                                 Bfr[ks], acc,
                                                                 0, 0, 0);
                #pragma unroll
                for (int rr = 0; rr < 4; ++rr) {
                    const float e2 = __builtin_amdgcn_exp2f(acc[rr] + b1v[ct]);
                    const float th =
                        fmaf(-2.0f, __builtin_amdgcn_rcpf(1.0f + e2), 1.0f);
                    s[pt][rr] = fmaf(w2v[ct], th, s[pt][rr]);
                }
            }
        }
        #pragma unroll
        for (int pt = 0; pt < 2; ++pt) {
            #pragma unroll
            for (int rr = 0; rr < 4; ++rr) {
                float v = s[pt][rr];
                v += __shfl_xor(v, 1);
                v += __shfl_xor(v, 2);
                v += __shfl_xor(v, 4);
                v += __shfl_xor(v, 8);
                if (c == 0) sc[(w * 2 + pt) * 16 + q * 4 + rr] = v + b2v;
            }
        }
        __syncthreads();
        if (tid < 128) {
            const float sv = sc[tid];
            float m = sv;
            for (int off = 32; off; off >>= 1) m = fmaxf(m, __shfl_xor(m, off));
            const float e = __expf(sv - m);
            float sum = e;
            for (int off = 32; off; off >>= 1) sum += __shfl_xor(sum, off);
            attn[pos0 + tid] = e / sum;
        }
        __syncthreads();
    }
}

// ---------------------------------------------------------------------------
// K3b: packet_emb[n,d] = sum_l attn[l,n]*h[l,n,d]. grid 512 (4 n each),
// block 256. 8-deep explicit load batching (latency-limited loop).
__global__ __launch_bounds__(256) void k_packet_emb(
    const __half* __restrict__ hF, const __half* __restrict__ hB,
    const float* __restrict__ attn, float* __restrict__ pe) {
    const int tid = threadIdx.x;
    const int g = tid >> 6;          // n group
    const int lane = tid & 63;
    const int n = blockIdx.x * 4 + g;
    const bool isF = lane < 32;
    const int chunk = lane & 31;     // 4 f16 per chunk
    const __half* __restrict__ hsrc = (isF ? hF : hB) + (size_t)n * 128 + chunk * 4;
    float acc0 = 0.f, acc1 = 0.f, acc2 = 0.f, acc3 = 0.f;
    for (int l0 = 0; l0 < 128; l0 += 8) {
        float wv[8];
        uint2 u[8];
        #pragma unroll
        for (int k = 0; k < 8; ++k) {
            wv[k] = attn[(l0 + k) * 2048 + n];
            u[k] = *reinterpret_cast<const uint2*>(hsrc +
                                                   (size_t)(l0 + k) * 2048 * 128);
        }
        #pragma unroll
        for (int k = 0; k < 8; ++k) {
            const f16* hv = reinterpret_cast<const f16*>(&u[k]);
            acc0 = fmaf(wv[k], (float)hv[0], acc0);
            acc1 = fmaf(wv[k], (float)hv[1], acc1);
            acc2 = fmaf(wv[k], (float)hv[2], acc2);
            acc3 = fmaf(wv[k], (float)hv[3], acc3);
        }
    }
    float4 o = {acc0, acc1, acc2, acc3};
    *reinterpret_cast<float4*>(&pe[n * 256 + (isF ? 0 : 128) + chunk * 4]) = o;
}

// ---------------------------------------------------------------------------
// K4pre: packed xg4[row*128+j] = {scl_rz*(xr+bhh_r), scl_rz*(xz+bhh_z), scl_n*xn, 0}.
// grid (256,2), block 384.
__global__ __launch_bounds__(384) void k_pkt_xg(
    const float* __restrict__ pe, const float* __restrict__ wihTF,
    const float* __restrict__ bihF, const float* __restrict__ bhhF,
    const float* __restrict__ wihTB, const float* __restrict__ bihB,
    const float* __restrict__ bhhB, float4* __restrict__ xg4F,
    float4* __restrict__ xg4B) {
    const int dir = blockIdx.y;
    const float* __restrict__ wihT = dir ? wihTB : wihTF;
    const float* __restrict__ bih = dir ? bihB : bihF;
    const float* __restrict__ bhh = dir ? bhhB : bhhF;
    float4* __restrict__ xg4 = dir ? xg4B : xg4F;
    const int rbase = blockIdx.x * 8;
    __shared__ float xrow[8][256];
    __shared__ float sh[8][384];
    for (int i = threadIdx.x; i < 8 * 256; i += 384)
        xrow[i >> 8][i & 255] = pe[rbase * 256 + i];
    __syncthreads();
    const int g = threadIdx.x;
    float acc[8];
    const float bias = bih[g] + (g < 256 ? bhh[g] : 0.0f);
    #pragma unroll
    for (int r = 0; r < 8; ++r) acc[r] = bias;
    for (int d = 0; d < 256; ++d) {
        const float w = wihT[d * 384 + g];
        #pragma unroll
        for (int r = 0; r < 8; ++r) acc[r] = fmaf(w, xrow[r][d], acc[r]);
    }
    const float scl = (g < 256) ? SCL_RZ : SCL_N;
    #pragma unroll
    for (int r = 0; r < 8; ++r) sh[r][g] = scl * acc[r];
    __syncthreads();
    for (int i = threadIdx.x; i < 8 * 128; i += 384) {
        const int r = i >> 7, jj = i & 127;
        float4 pk;
        pk.x = sh[r][jj];
        pk.y = sh[r][jj + 128];
        pk.z = sh[r][jj + 256];
        pk.w = 0.f;
        xg4[(size_t)(rbase + r) * 128 + jj] = pk;
    }
}

// ---------------------------------------------------------------------------
// K4: packet BiGRU via MFMA f16. grid 8, block 512 (8 waves), 32 steps.
__global__ __launch_bounds__(512, 1) void k_pkt_gru(
    const float4* __restrict__ xg4F, const float4* __restrict__ xg4B,
    const float* __restrict__ whhF, const float* __restrict__ whhB,
    const float* __restrict__ bhhF, const float* __restrict__ bhhB,
    float* __restrict__ h2F, float* __restrict__ h2B) {
    const int dir = blockIdx.x & 1;
    const int chunk = blockIdx.x >> 1;  // 0..3
    const int row0 = chunk * 16;
    const int tid = threadIdx.x;
    const int wid = tid >> 6;
    const int lane = tid & 63;
    const int c = lane & 15;
    const int q = lane >> 4;
    const int j = wid * 16 + c;

    const float4* __restrict__ xg4 = dir ? xg4B : xg4F;
    const float* __restrict__ whh = dir ? whhB : whhF;
    const float* __restrict__ bhh = dir ? bhhB : bhhF;
    float* __restrict__ hout = dir ? h2B : h2F;

    __shared__ f16 hbuf[2][16 * 128];

    for (int i = tid; i < 16 * 128; i += 512) hbuf[0][i] = (f16)0.f;

    f16x8 Bf[3][4];
    #pragma unroll
    for (int g = 0; g < 3; ++g) {
        const float scl = (g == 2) ? SCL_N : SCL_RZ;
        #pragma unroll
        for (int ks = 0; ks < 4; ++ks) {
            const float* src = whh + (size_t)(g * 128 + j) * 128 + ks * 32 + q * 8;
            f16x8 b;
            #pragma unroll
            for (int e = 0; e < 8; ++e) b[e] = (f16)(scl * src[e]);
            Bf[g][ks] = b;
        }
    }
    const float bh2 = SCL_N * bhh[j + 256];
    float hold[4];
    #pragma unroll
    for (int rr = 0; rr < 4; ++rr) hold[rr] = 0.f;
    __syncthreads();

    for (int t = 0; t < 32; ++t) {
        const int curb = t & 1, nxtb = curb ^ 1;
        const int tt = dir ? (31 - t) : t;

        float4 x4[4];
        #pragma unroll
        for (int rr = 0; rr < 4; ++rr)
            x4[rr] = xg4[(size_t)(tt * 64 + row0 + q * 4 + rr) * 128 + j];

        f16x8 Af[4];
        #pragma unroll
        for (int ks = 0; ks < 4; ++ks) {
            const int kb = ks * 32 + q * 8;
            const int idx = c * 128 + (kb ^ ((c & 7) << 3));
            Af[ks] = *reinterpret_cast<const f16x8*>(&hbuf[curb][idx]);
        }

        f32x4 a0 = {0.f, 0.f, 0.f, 0.f};
        f32x4 a1 = {0.f, 0.f, 0.f, 0.f};
        f32x4 a2 = {0.f, 0.f, 0.f, 0.f};
        #pragma unroll
        for (int ks = 0; ks < 4; ++ks) {
            a0 = __builtin_amdgcn_mfma_f32_16x16x32_f16(Af[ks], Bf[0][ks], a0, 0, 0, 0);
            a1 = __builtin_amdgcn_mfma_f32_16x16x32_f16(Af[ks], Bf[1][ks], a1, 0, 0, 0);
            a2 = __builtin_amdgcn_mfma_f32_16x16x32_f16(Af[ks], Bf[2][ks], a2, 0, 0, 0);
        }

        #pragma unroll
        for (int rr = 0; rr < 4; ++rr) {
            const float e0 = __builtin_amdgcn_exp2f(x4[rr].x + a0[rr]);
            const float rg = __builtin_amdgcn_rcpf(1.0f + e0);
            const float e1 = __builtin_amdgcn_exp2f(x4[rr].y + a1[rr]);
            const float zg = __builtin_amdgcn_rcpf(1.0f + e1);
            const float e2 =
                __builtin_amdgcn_exp2f(x4[rr].z + rg * (a2[rr] + bh2));
            const float ng = fmaf(-2.0f, __builtin_amdgcn_rcpf(1.0f + e2), 1.0f);
            const float hn = fmaf(zg, hold[rr] - ng, ng);
            hold[rr] = hn;
            const int row = q * 4 + rr;
            hbuf[nxtb][row * 128 + (j ^ ((row & 7) << 3))] = (f16)hn;
            hout[((size_t)tt * 64 + row0 + row) * 128 + j] = hn;
        }
        lds_barrier();
    }
}

// ---------------------------------------------------------------------------
// K5a: packet attention scores. grid 2048 (n), block 128.
__global__ __launch_bounds__(128) void k_scores2(
    const float* __restrict__ h2F, const float* __restrict__ h2B,
    const float* __restrict__ paw1,  // [128][256] row-major
    const float* __restrict__ pab1, const float* __restrict__ paw2,
    const float* __restrict__ pab2, float* __restrict__ scores2) {
    const int n = blockIdx.x;
    const int tid = threadIdx.x;  // 128
    __shared__ float x[256];
    __shared__ float red[2];
    x[tid] = h2F[n * 128 + tid];
    x[tid + 128] = h2B[n * 128 + tid];
    __syncthreads();
    float acc = pab1[tid];
    const float* wr = paw1 + tid * 256;
    #pragma unroll 8
    for (int d = 0; d < 256; ++d) acc = fmaf(wr[d], x[d], acc);
    float s = paw2[tid] * fast_tanh(acc);
    s += __shfl_xor(s, 1);
    s += __shfl_xor(s, 2);
    s += __shfl_xor(s, 4);
    s += __shfl_xor(s, 8);
    s += __shfl_xor(s, 16);
    s += __shfl_xor(s, 32);
    if ((tid & 63) == 0) red[tid >> 6] = s;
    __syncthreads();
    if (tid == 0) scores2[n] = red[0] + red[1] + pab2[0];
}

// ---------------------------------------------------------------------------
// K5b: softmax over b + weighted sum + final FC. grid 32 (p), block 256.
__global__ __launch_bounds__(256) void k_final3(
    const float* __restrict__ h2F, const float* __restrict__ h2B,
    const float* __restrict__ scores2, const float* __restrict__ wf,
    const float* __restrict__ bfv, float* __restrict__ outp) {
    const int p = blockIdx.x;
    const int tid = threadIdx.x;
    __shared__ float sc[64];
    __shared__ float femb[256];
    __shared__ float red[64];

    if (tid < 64) {
        const float s = scores2[p * 64 + tid];
        float m = s;
        for (int off = 32; off; off >>= 1) m = fmaxf(m, __shfl_xor(m, off));
        const float e = __expf(s - m);
        float sum = e;
        for (int off = 32; off; off >>= 1) sum += __shfl_xor(sum, off);
        sc[tid] = e / sum;
    }
    __syncthreads();

    {
        const float* __restrict__ hsrc = (tid < 128) ? h2F : h2B;
        const int d = tid & 127;
        float acc = 0.f;
        for (int b = 0; b < 64; ++b)
            acc = fmaf(sc[b], hsrc[(p * 64 + b) * 128 + d], acc);
        femb[tid] = acc;
    }
    __syncthreads();

    const float fv = femb[tid];
    #pragma unroll
    for (int c = 0; c < 10; ++c) {
        float s = fv * wf[c * 256 + tid];
        s += __shfl_xor(s, 1);
        s += __shfl_xor(s, 2);
        s += __shfl_xor(s, 4);
        s += __shfl_xor(s, 8);
        s += __shfl_xor(s, 16);
        s += __shfl_xor(s, 32);
        if ((tid & 63) == 0) red[(c << 2) | (tid >> 6)] = s;
        __syncthreads();
        if (tid == 0)
            outp[p * 10 + c] = bfv[c] + red[c << 2] + red[(c << 2) | 1] +
                               red[(c << 2) | 2] + red[(c << 2) | 3];
        __syncthreads();
    }
}

// ---------------------------------------------------------------------------
extern "C" void kernel_launch(void* const* d_in, const int* in_sizes, int n_in,
                              void* d_out, int out_size, void* d_ws,
                              size_t ws_size, hipStream_t stream) {
    const int* flow = (const int*)d_in[0];
    const float* emb = (const float*)d_in[1];
    const float* byte_wih_f = (const float*)d_in[2];
    const float* byte_whh_f = (const float*)d_in[3];
    const float* byte_bih_f = (const float*)d_in[4];
    const float* byte_bhh_f = (const float*)d_in[5];
    const float* byte_wih_b = (const float*)d_in[6];
    const float* byte_whh_b = (const float*)d_in[7];
    const float* byte_bih_b = (const float*)d_in[8];
    const float* byte_bhh_b = (const float*)d_in[9];
    const float* pkt_wih_f = (const float*)d_in[10];
    const float* pkt_whh_f = (const float*)d_in[11];
    const float* pkt_bih_f = (const float*)d_in[12];
    const float* pkt_bhh_f = (const float*)d_in[13];
    const float* pkt_wih_b = (const float*)d_in[14];
    const float* pkt_whh_b = (const float*)d_in[15];
    const float* pkt_bih_b = (const float*)d_in[16];
    const float* pkt_bhh_b = (const float*)d_in[17];
    const float* ba_w1 = (const float*)d_in[18];
    const float* ba_b1 = (const float*)d_in[19];
    const float* ba_w2 = (const float*)d_in[20];
    const float* ba_b2 = (const float*)d_in[21];
    const float* pa_w1 = (const float*)d_in[22];
    const float* pa_b1 = (const float*)d_in[23];
    const float* pa_w2 = (const float*)d_in[24];
    const float* pa_b2 = (const float*)d_in[25];
    const float* wf = (const float*)d_in[26];
    const float* bf = (const float*)d_in[27];

    char* base = (char*)d_ws;
    size_t off = 0;
    auto allocf = [&](size_t nf) -> float* {
        float* p = (float*)(base + off);
        off += nf * sizeof(float);
        return p;
    };
    auto alloch = [&](size_t nh) -> __half* {
        off = (off + 255) & ~(size_t)255;
        __half* p = (__half*)(base + off);
        off += nh * sizeof(__half);
        return p;
    };
    float* wihTpF = allocf(256 * 384);
    float* wihTpB = allocf(256 * 384);
    float* attn = allocf(262144);
    float* pe = allocf(2048 * 256);
    float4* tab4F = (float4*)allocf(256 * 128 * 4);
    float4* tab4B = (float4*)allocf(256 * 128 * 4);
    float4* xg4F = (float4*)allocf((size_t)2048 * 128 * 4);
    float4* xg4B = (float4*)allocf((size_t)2048 * 128 * 4);
    float* h2F = allocf(32 * 64 * 128);
    float* h2B = allocf(32 * 64 * 128);
    float* scores2 = allocf(2048);
    __half* w1h = alloch(128 * 256);
    __half* hF = alloch((size_t)128 * 2048 * 128);
    __half* hB = alloch((size_t)128 * 2048 * 128);
    if (off > ws_size) return;  // diagnostic: leaves d_out poisoned
    (void)in_sizes; (void)n_in; (void)out_size;

    k_tables_w1<<<832, 384, 0, stream>>>(emb, byte_wih_f, byte_bih_f,
                                         byte_bhh_f, byte_wih_b, byte_bih_b,
                                         byte_bhh_b, tab4F, tab4B, ba_w1,
                                         (f16*)w1h, pkt_wih_f, pkt_wih_b,
                                         wihTpF, wihTpB);

    k_byte_gru<<<256, 512, 0, stream>>>(flow, tab4F, tab4B, byte_whh_f,
                                        byte_whh_b, byte_bhh_f, byte_bhh_b, hF,
                                        hB);

    k_scores_attn<<<1024, 256, 0, stream>>>(hF, hB, (const f16*)w1h, ba_b1,
                                            ba_w2, ba_b2, attn);
    k_packet_emb<<<512, 256, 0, stream>>>(hF, hB, attn, pe);

    k_pkt_xg<<<dim3(256, 2), 384, 0, stream>>>(pe, wihTpF, pkt_bih_f,
                                               pkt_bhh_f, wihTpB, pkt_bih_b,
                                               pkt_bhh_b, xg4F, xg4B);
    k_pkt_gru<<<8, 512, 0, stream>>>(xg4F, xg4B, pkt_whh_f, pkt_whh_b,
                                     pkt_bhh_f, pkt_bhh_b, h2F, h2B);
    k_scores2<<<2048, 128, 0, stream>>>(h2F, h2B, pa_w1, pa_b1, pa_w2, pa_b2,
                                        scores2);
    k_final3<<<32, 256, 0, stream>>>(h2F, h2B, scores2, wf, bf, (float*)d_out);
}

// Round 14
// 273.399 us; speedup vs baseline: 1.1206x; 1.0334x over previous
//
#include <hip/hip_runtime.h>
#include <hip/hip_bf16.h>
#include <hip/hip_fp16.h>
#include <cstdint>
#include <cstddef>

// P=32, B=64, L=128, E=64, HB=128, HP=128, G=384, N=P*B=2048, PE=256, LH=128, NC=10
// Gate scaling folded into weights/tables: r,z pre-scaled by -log2(e),
// n pre-scaled by 2*log2(e)  =>  sigmoid = rcp(1+exp2(x)), tanh = 1-2*rcp(1+exp2(x)).

#define DINLINE __device__ __forceinline__

typedef _Float16 f16;
typedef f16 f16x8 __attribute__((ext_vector_type(8)));
typedef float f32x4 __attribute__((ext_vector_type(4)));

#define SCL_RZ (-1.44269504089f)
#define SCL_N (2.88539008178f)

static DINLINE float fast_tanh(float x) {  // unscaled-input version (scores2)
    const float e = __builtin_amdgcn_exp2f(2.88539008178f * x);
    return 1.0f - 2.0f * __builtin_amdgcn_rcpf(1.0f + e);
}

// LDS-only barrier: ds ops ordered, global stores stay in flight (no vmcnt drain)
static DINLINE void lds_barrier() {
    asm volatile("s_waitcnt lgkmcnt(0)\n\ts_barrier" ::: "memory");
    __builtin_amdgcn_sched_barrier(0);
}

// ---------------------------------------------------------------------------
// K0: byte tables (scaled, packed float4) + ba_w1 f16 swizzle prep (scaled)
//     + pkt_wih transposes. grid 832, block 384.
__global__ void k_tables_w1(const float* __restrict__ emb,
                            const float* __restrict__ wihF, const float* __restrict__ bihF,
                            const float* __restrict__ bhhF,
                            const float* __restrict__ wihB, const float* __restrict__ bihB,
                            const float* __restrict__ bhhB,
                            float4* __restrict__ tab4F, float4* __restrict__ tab4B,
                            const float* __restrict__ w1, f16* __restrict__ w1h,
                            const float* __restrict__ pwihF, const float* __restrict__ pwihB,
                            float* __restrict__ wihTpF, float* __restrict__ wihTpB) {
    if (blockIdx.x >= 640) {  // transposes: 2 matrices x 96 blocks
        const int bid = blockIdx.x - 640;
        const int m = bid / 96, bx = bid % 96;
        const float* __restrict__ s = m ? pwihB : pwihF;
        float* __restrict__ d = m ? wihTpB : wihTpF;
        for (int idx = bx * 384 + threadIdx.x; idx < 384 * 256; idx += 96 * 384) {
            const int r = idx >> 8, c = idx & 255;
            d[c * 384 + r] = s[idx];
        }
        return;
    }
    if (blockIdx.x >= 512) {  // w1 prep
        const int col = blockIdx.x - 512;  // 0..127
        const int k = threadIdx.x;
        if (k < 256)
            w1h[col * 256 + (k ^ ((col & 7) << 3))] =
                (f16)(SCL_N * w1[col * 256 + k]);
        return;
    }
    const int v = blockIdx.x & 255;
    const int dir = blockIdx.x >> 8;
    const float* wih = dir ? wihB : wihF;
    const float* bih = dir ? bihB : bihF;
    const float* bhh = dir ? bhhB : bhhF;
    float4* tab4 = dir ? tab4B : tab4F;
    __shared__ float er[64];
    __shared__ float sh[384];
    if (threadIdx.x < 64) er[threadIdx.x] = emb[v * 64 + threadIdx.x];
    __syncthreads();
    const int g = threadIdx.x;  // 384 threads
    float acc = bih[g] + (g < 256 ? bhh[g] : 0.0f);
    #pragma unroll
    for (int e = 0; e < 64; ++e) acc = fmaf(wih[g * 64 + e], er[e], acc);
    sh[g] = acc * (g < 256 ? SCL_RZ : SCL_N);
    __syncthreads();
    if (g < 128) {
        float4 pk;
        pk.x = sh[g];
        pk.y = sh[g + 128];
        pk.z = sh[g + 256];
        pk.w = 0.f;
        tab4[v * 128 + g] = pk;
    }
}

// ---------------------------------------------------------------------------
// K2: byte BiGRU via MFMA f16. flow_lds [t][row], direct strided h stores.
__global__ __launch_bounds__(512, 1) void k_byte_gru(
    const int* __restrict__ flow,
    const float4* __restrict__ tab4F, const float4* __restrict__ tab4B,
    const float* __restrict__ whhF, const float* __restrict__ whhB,
    const float* __restrict__ bhhF, const float* __restrict__ bhhB,
    __half* __restrict__ hF, __half* __restrict__ hB) {
    const int dir = blockIdx.x & 1;
    const int chunk = blockIdx.x >> 1;  // 0..127
    const int row0 = chunk * 16;
    const int tid = threadIdx.x;
    const int wid = tid >> 6;
    const int lane = tid & 63;
    const int c = lane & 15;
    const int q = lane >> 4;
    const int j = wid * 16 + c;  // h-col this lane produces

    const char* __restrict__ t4j =
        reinterpret_cast<const char*>(dir ? tab4B : tab4F) + (j << 4);
    const float* __restrict__ whh = dir ? whhB : whhF;
    const float* __restrict__ bhh = dir ? bhhB : bhhF;
    __half* __restrict__ hout = dir ? hB : hF;

    __shared__ f16 hbuf[2][16 * 128];   // swizzled: row*128 + (k ^ ((row&7)<<3))
    __shared__ int flow_lds[128][16];   // [t][row], pre-scaled v*2048 (byte off)

    for (int i = tid; i < 16 * 128; i += 512) {
        const int row = i >> 7, t = i & 127;
        flow_lds[t][row] = (flow[row0 * 128 + i] & 255) << 11;
    }
    for (int i = tid; i < 16 * 128; i += 512) hbuf[0][i] = (f16)0.f;

    // B fragments: B[k][col] = scl(g)*whh[(g*128+j)][k]
    f16x8 Bf[3][4];
    #pragma unroll
    for (int g = 0; g < 3; ++g) {
        const float scl = (g == 2) ? SCL_N : SCL_RZ;
        #pragma unroll
        for (int ks = 0; ks < 4; ++ks) {
            const float* src = whh + (size_t)(g * 128 + j) * 128 + ks * 32 + q * 8;
            f16x8 b;
            #pragma unroll
            for (int e = 0; e < 8; ++e) b[e] = (f16)(scl * src[e]);
            Bf[g][ks] = b;
        }
    }
    const float bh2 = SCL_N * bhh[j + 256];  // r,z biases folded into tab4
    float hold[4];
    #pragma unroll
    for (int rr = 0; rr < 4; ++rr) hold[rr] = 0.f;

    // strided store pointer: advances +/- one timestep per iteration
    const int tt0 = dir ? 127 : 0;
    __half* hp = hout + ((size_t)tt0 * 2048 + row0 + q * 4) * 128 + j;
    const ptrdiff_t hstep = (dir ? -1 : 1) * (ptrdiff_t)2048 * 128;
    __syncthreads();

    for (int t = 0; t < 128; ++t) {
        const int curb = t & 1, nxtb = curb ^ 1;
        const int tt = dir ? (127 - t) : t;

        // one b128 read: 4 rows' table byte-offsets for step tt
        const int4 off4 = *reinterpret_cast<const int4*>(&flow_lds[tt][q * 4]);
        float4 x4[4];
        x4[0] = *reinterpret_cast<const float4*>(t4j + off4.x);
        x4[1] = *reinterpret_cast<const float4*>(t4j + off4.y);
        x4[2] = *reinterpret_cast<const float4*>(t4j + off4.z);
        x4[3] = *reinterpret_cast<const float4*>(t4j + off4.w);

        // A fragments (row = c, k = ks*32 + q*8 + e, swizzled)
        f16x8 Af[4];
        #pragma unroll
        for (int ks = 0; ks < 4; ++ks) {
            const int kb = ks * 32 + q * 8;
            const int idx = c * 128 + (kb ^ ((c & 7) << 3));
            Af[ks] = *reinterpret_cast<const f16x8*>(&hbuf[curb][idx]);
        }

        f32x4 a0 = {0.f, 0.f, 0.f, 0.f};
        f32x4 a1 = {0.f, 0.f, 0.f, 0.f};
        f32x4 a2 = {0.f, 0.f, 0.f, 0.f};
        #pragma unroll
        for (int ks = 0; ks < 4; ++ks) {
            a0 = __builtin_amdgcn_mfma_f32_16x16x32_f16(Af[ks], Bf[0][ks], a0, 0, 0, 0);
            a1 = __builtin_amdgcn_mfma_f32_16x16x32_f16(Af[ks], Bf[1][ks], a1, 0, 0, 0);
            a2 = __builtin_amdgcn_mfma_f32_16x16x32_f16(Af[ks], Bf[2][ks], a2, 0, 0, 0);
        }

        #pragma unroll
        for (int rr = 0; rr < 4; ++rr) {
            const float e0 = __builtin_amdgcn_exp2f(x4[rr].x + a0[rr]);
            const float rg = __builtin_amdgcn_rcpf(1.0f + e0);
            const float e1 = __builtin_amdgcn_exp2f(x4[rr].y + a1[rr]);
            const float zg = __builtin_amdgcn_rcpf(1.0f + e1);
            const float e2 =
                __builtin_amdgcn_exp2f(x4[rr].z + rg * (a2[rr] + bh2));
            const float ng = fmaf(-2.0f, __builtin_amdgcn_rcpf(1.0f + e2), 1.0f);
            const float hn = fmaf(zg, hold[rr] - ng, ng);
            hold[rr] = hn;
            const int row = q * 4 + rr;
            hbuf[nxtb][row * 128 + (j ^ ((row & 7) << 3))] = (f16)hn;
            hp[rr * 128] = (__half)hn;  // direct store, never drained in-loop
        }
        hp += hstep;
        lds_barrier();
    }
}

// ---------------------------------------------------------------------------
// K3: byte attention scores + softmax fused. grid 1024 (256 positions each),
// block 256 (4 waves). W1 staged from pre-converted f16 swizzled+scaled buffer.
__global__ __launch_bounds__(256, 1) void k_scores_attn(
    const __half* __restrict__ hF, const __half* __restrict__ hB,
    const f16* __restrict__ w1h,  // [128*256] f16 pre-swizzled, *SCL_N
    const float* __restrict__ b1, const float* __restrict__ w2,
    const float* __restrict__ b2, float* __restrict__ attn) {
    __shared__ f16 w1lds[128 * 256];  // 64 KB
    __shared__ float sc[128];
    const int tid = threadIdx.x;
    {
        const uint2* src = reinterpret_cast<const uint2*>(w1h);
        uint2* dst = reinterpret_cast<uint2*>(w1lds);
        for (int i = tid; i < 8192; i += 256) dst[i] = src[i];
    }
    const int lane = tid & 63, w = tid >> 6;
    const int c = lane & 15, q = lane >> 4;

    float b1v[8], w2v[8];
    #pragma unroll
    for (int ct = 0; ct < 8; ++ct) {
        b1v[ct] = SCL_N * b1[ct * 16 + c];
        w2v[ct] = w2[ct * 16 + c];
    }
    const float b2v = b2[0];
    __syncthreads();

    for (int it = 0; it < 2; ++it) {
        const int pos0 = blockIdx.x * 256 + it * 128;

        f16x8 Af[2][8];
        #pragma unroll
        for (int pt = 0; pt < 2; ++pt) {
            const size_t pos = (size_t)pos0 + (w * 2 + pt) * 16 + c;
            const f16* hFp = (const f16*)(hF + pos * 128);
            const f16* hBp = (const f16*)(hB + pos * 128);
            #pragma unroll
            for (int ks = 0; ks < 4; ++ks)
                Af[pt][ks] = *reinterpret_cast<const f16x8*>(hFp + ks * 32 + q * 8);
            #pragma unroll
            for (int ks = 0; ks < 4; ++ks)
                Af[pt][4 + ks] = *reinterpret_cast<const f16x8*>(hBp + ks * 32 + q * 8);
        }

        float s[2][4] = {{0.f, 0.f, 0.f, 0.f}, {0.f, 0.f, 0.f, 0.f}};
        #pragma unroll
        for (int ct = 0; ct < 8; ++ct) {
            const int jj = ct * 16 + c;
            f16x8 Bfr[8];
            #pragma unroll
            for (int ks = 0; ks < 8; ++ks) {
                const int k = ks * 32 + q * 8;
                Bfr[ks] = *reinterpret_cast<const f16x8*>(
                    &w1lds[jj * 256 + (k ^ ((jj & 7) << 3))]);
            }
            #pragma unroll
            for (int pt = 0; pt < 2; ++pt) {
                f32x4 acc = {0.f, 0.f, 0.f, 0.f};
                #pragma unroll
                for (int ks = 0; ks < 8; ++ks)
                    acc = __builtin_amdgcn_mfma_f32_16x16x32_f16(Af[pt][ks],
                                                                 Bfr[ks], acc,
                                                                 0, 0, 0);
                #pragma unroll
                for (int rr = 0; rr < 4; ++rr) {
                    const float e2 = __builtin_amdgcn_exp2f(acc[rr] + b1v[ct]);
                    const float th =
                        fmaf(-2.0f, __builtin_amdgcn_rcpf(1.0f + e2), 1.0f);
                    s[pt][rr] = fmaf(w2v[ct], th, s[pt][rr]);
                }
            }
        }
        #pragma unroll
        for (int pt = 0; pt < 2; ++pt) {
            #pragma unroll
            for (int rr = 0; rr < 4; ++rr) {
                float v = s[pt][rr];
                v += __shfl_xor(v, 1);
                v += __shfl_xor(v, 2);
                v += __shfl_xor(v, 4);
                v += __shfl_xor(v, 8);
                if (c == 0) sc[(w * 2 + pt) * 16 + q * 4 + rr] = v + b2v;
            }
        }
        __syncthreads();
        if (tid < 128) {
            const float sv = sc[tid];
            float m = sv;
            for (int off = 32; off; off >>= 1) m = fmaxf(m, __shfl_xor(m, off));
            const float e = __expf(sv - m);
            float sum = e;
            for (int off = 32; off; off >>= 1) sum += __shfl_xor(sum, off);
            attn[pos0 + tid] = e / sum;
        }
        __syncthreads();
    }
}

// ---------------------------------------------------------------------------
// K3b: packet_emb. grid 1024 (2 n each), block 256: 2 waves per n (64 l each,
// 8-deep load batching), LDS reduce.
__global__ __launch_bounds__(256) void k_packet_emb(
    const __half* __restrict__ hF, const __half* __restrict__ hB,
    const float* __restrict__ attn, float* __restrict__ pe) {
    const int tid = threadIdx.x;
    const int w = tid >> 6;          // wave 0..3
    const int lane = tid & 63;
    const int n = blockIdx.x * 2 + (w >> 1);
    const int l0 = (w & 1) * 64;
    const bool isF = lane < 32;
    const int chunk = lane & 31;     // 4 f16 per chunk
    const __half* __restrict__ hsrc = (isF ? hF : hB) + (size_t)n * 128 + chunk * 4;
    float acc0 = 0.f, acc1 = 0.f, acc2 = 0.f, acc3 = 0.f;
    for (int lb = 0; lb < 64; lb += 8) {
        float wv[8];
        uint2 u[8];
        #pragma unroll
        for (int k = 0; k < 8; ++k) {
            const int l = l0 + lb + k;
            wv[k] = attn[l * 2048 + n];
            u[k] = *reinterpret_cast<const uint2*>(hsrc + (size_t)l * 2048 * 128);
        }
        #pragma unroll
        for (int k = 0; k < 8; ++k) {
            const f16* hv = reinterpret_cast<const f16*>(&u[k]);
            acc0 = fmaf(wv[k], (float)hv[0], acc0);
            acc1 = fmaf(wv[k], (float)hv[1], acc1);
            acc2 = fmaf(wv[k], (float)hv[2], acc2);
            acc3 = fmaf(wv[k], (float)hv[3], acc3);
        }
    }
    __shared__ float4 part[4][64];
    part[w][lane] = (float4){acc0, acc1, acc2, acc3};
    __syncthreads();
    if ((w & 1) == 0) {
        const float4 a = part[w][lane];
        const float4 b = part[w + 1][lane];
        float4 o = {a.x + b.x, a.y + b.y, a.z + b.z, a.w + b.w};
        *reinterpret_cast<float4*>(&pe[n * 256 + (isF ? 0 : 128) + chunk * 4]) = o;
    }
}

// ---------------------------------------------------------------------------
// K4pre: packed xg4[row*128+j] = {scl_rz*(xr+bhh_r), scl_rz*(xz+bhh_z), scl_n*xn, 0}.
// grid (256,2), block 384.
__global__ __launch_bounds__(384) void k_pkt_xg(
    const float* __restrict__ pe, const float* __restrict__ wihTF,
    const float* __restrict__ bihF, const float* __restrict__ bhhF,
    const float* __restrict__ wihTB, const float* __restrict__ bihB,
    const float* __restrict__ bhhB, float4* __restrict__ xg4F,
    float4* __restrict__ xg4B) {
    const int dir = blockIdx.y;
    const float* __restrict__ wihT = dir ? wihTB : wihTF;
    const float* __restrict__ bih = dir ? bihB : bihF;
    const float* __restrict__ bhh = dir ? bhhB : bhhF;
    float4* __restrict__ xg4 = dir ? xg4B : xg4F;
    const int rbase = blockIdx.x * 8;
    __shared__ float xrow[8][256];
    __shared__ float sh[8][384];
    for (int i = threadIdx.x; i < 8 * 256; i += 384)
        xrow[i >> 8][i & 255] = pe[rbase * 256 + i];
    __syncthreads();
    const int g = threadIdx.x;
    float acc[8];
    const float bias = bih[g] + (g < 256 ? bhh[g] : 0.0f);
    #pragma unroll
    for (int r = 0; r < 8; ++r) acc[r] = bias;
    for (int d = 0; d < 256; ++d) {
        const float w = wihT[d * 384 + g];
        #pragma unroll
        for (int r = 0; r < 8; ++r) acc[r] = fmaf(w, xrow[r][d], acc[r]);
    }
    const float scl = (g < 256) ? SCL_RZ : SCL_N;
    #pragma unroll
    for (int r = 0; r < 8; ++r) sh[r][g] = scl * acc[r];
    __syncthreads();
    for (int i = threadIdx.x; i < 8 * 128; i += 384) {
        const int r = i >> 7, jj = i & 127;
        float4 pk;
        pk.x = sh[r][jj];
        pk.y = sh[r][jj + 128];
        pk.z = sh[r][jj + 256];
        pk.w = 0.f;
        xg4[(size_t)(rbase + r) * 128 + jj] = pk;
    }
}

// ---------------------------------------------------------------------------
// K4: packet BiGRU via MFMA f16. grid 32 (dir=bx&1, chunk=bx>>1: 4 rows),
// block 512 (8 waves), 32 steps. 1 gate-cell per lane: physical row pr
// (0..3) lives at LDS slot pr*4; acc reg 0 of lane group q holds C row q*4.
__global__ __launch_bounds__(512, 1) void k_pkt_gru(
    const float4* __restrict__ xg4F, const float4* __restrict__ xg4B,
    const float* __restrict__ whhF, const float* __restrict__ whhB,
    const float* __restrict__ bhhF, const float* __restrict__ bhhB,
    float* __restrict__ h2F, float* __restrict__ h2B) {
    const int dir = blockIdx.x & 1;
    const int chunk = blockIdx.x >> 1;  // 0..15
    const int row0 = chunk * 4;
    const int tid = threadIdx.x;
    const int wid = tid >> 6;
    const int lane = tid & 63;
    const int c = lane & 15;
    const int q = lane >> 4;
    const int j = wid * 16 + c;

    const float4* __restrict__ xg4 = dir ? xg4B : xg4F;
    const float* __restrict__ whh = dir ? whhB : whhF;
    const float* __restrict__ bhh = dir ? bhhB : bhhF;
    float* __restrict__ hout = dir ? h2B : h2F;

    __shared__ f16 hbuf[2][16 * 128];  // slots pr*4 live, others stay zero

    {
        f16* hb = reinterpret_cast<f16*>(hbuf);
        for (int i = tid; i < 2 * 16 * 128; i += 512) hb[i] = (f16)0.f;
    }

    f16x8 Bf[3][4];
    #pragma unroll
    for (int g = 0; g < 3; ++g) {
        const float scl = (g == 2) ? SCL_N : SCL_RZ;
        #pragma unroll
        for (int ks = 0; ks < 4; ++ks) {
            const float* src = whh + (size_t)(g * 128 + j) * 128 + ks * 32 + q * 8;
            f16x8 b;
            #pragma unroll
            for (int e = 0; e < 8; ++e) b[e] = (f16)(scl * src[e]);
            Bf[g][ks] = b;
        }
    }
    const float bh2 = SCL_N * bhh[j + 256];
    float hold = 0.f;
    const int slot = q * 4;  // this lane's write slot (C row q*4, reg 0)
    __syncthreads();

    for (int t = 0; t < 32; ++t) {
        const int curb = t & 1, nxtb = curb ^ 1;
        const int tt = dir ? (31 - t) : t;

        const float4 x4 = xg4[(size_t)(tt * 64 + row0 + q) * 128 + j];

        f16x8 Af[4];
        #pragma unroll
        for (int ks = 0; ks < 4; ++ks) {
            const int kb = ks * 32 + q * 8;
            const int idx = c * 128 + (kb ^ ((c & 7) << 3));
            Af[ks] = *reinterpret_cast<const f16x8*>(&hbuf[curb][idx]);
        }

        f32x4 a0 = {0.f, 0.f, 0.f, 0.f};
        f32x4 a1 = {0.f, 0.f, 0.f, 0.f};
        f32x4 a2 = {0.f, 0.f, 0.f, 0.f};
        #pragma unroll
        for (int ks = 0; ks < 4; ++ks) {
            a0 = __builtin_amdgcn_mfma_f32_16x16x32_f16(Af[ks], Bf[0][ks], a0, 0, 0, 0);
            a1 = __builtin_amdgcn_mfma_f32_16x16x32_f16(Af[ks], Bf[1][ks], a1, 0, 0, 0);
            a2 = __builtin_amdgcn_mfma_f32_16x16x32_f16(Af[ks], Bf[2][ks], a2, 0, 0, 0);
        }

        {
            const float e0 = __builtin_amdgcn_exp2f(x4.x + a0[0]);
            const float rg = __builtin_amdgcn_rcpf(1.0f + e0);
            const float e1 = __builtin_amdgcn_exp2f(x4.y + a1[0]);
            const float zg = __builtin_amdgcn_rcpf(1.0f + e1);
            const float e2 = __builtin_amdgcn_exp2f(x4.z + rg * (a2[0] + bh2));
            const float ng = fmaf(-2.0f, __builtin_amdgcn_rcpf(1.0f + e2), 1.0f);
            const float hn = fmaf(zg, hold - ng, ng);
            hold = hn;
            hbuf[nxtb][slot * 128 + (j ^ ((slot & 7) << 3))] = (f16)hn;
            hout[((size_t)tt * 64 + row0 + q) * 128 + j] = hn;
        }
        lds_barrier();
    }
}

// ---------------------------------------------------------------------------
// K5a: packet attention scores. grid 2048 (n), block 128.
__global__ __launch_bounds__(128) void k_scores2(
    const float* __restrict__ h2F, const float* __restrict__ h2B,
    const float* __restrict__ paw1,  // [128][256] row-major
    const float* __restrict__ pab1, const float* __restrict__ paw2,
    const float* __restrict__ pab2, float* __restrict__ scores2) {
    const int n = blockIdx.x;
    const int tid = threadIdx.x;  // 128
    __shared__ float x[256];
    __shared__ float red[2];
    x[tid] = h2F[n * 128 + tid];
    x[tid + 128] = h2B[n * 128 + tid];
    __syncthreads();
    float acc = pab1[tid];
    const float* wr = paw1 + tid * 256;
    #pragma unroll 8
    for (int d = 0; d < 256; ++d) acc = fmaf(wr[d], x[d], acc);
    float s = paw2[tid] * fast_tanh(acc);
    s += __shfl_xor(s, 1);
    s += __shfl_xor(s, 2);
    s += __shfl_xor(s, 4);
    s += __shfl_xor(s, 8);
    s += __shfl_xor(s, 16);
    s += __shfl_xor(s, 32);
    if ((tid & 63) == 0) red[tid >> 6] = s;
    __syncthreads();
    if (tid == 0) scores2[n] = red[0] + red[1] + pab2[0];
}

// ---------------------------------------------------------------------------
// K5b: softmax over b + weighted sum + final FC. grid 32 (p), block 256.
__global__ __launch_bounds__(256) void k_final3(
    const float* __restrict__ h2F, const float* __restrict__ h2B,
    const float* __restrict__ scores2, const float* __restrict__ wf,
    const float* __restrict__ bfv, float* __restrict__ outp) {
    const int p = blockIdx.x;
    const int tid = threadIdx.x;
    __shared__ float sc[64];
    __shared__ float femb[256];
    __shared__ float red[64];

    if (tid < 64) {
        const float s = scores2[p * 64 + tid];
        float m = s;
        for (int off = 32; off; off >>= 1) m = fmaxf(m, __shfl_xor(m, off));
        const float e = __expf(s - m);
        float sum = e;
        for (int off = 32; off; off >>= 1) sum += __shfl_xor(sum, off);
        sc[tid] = e / sum;
    }
    __syncthreads();

    {
        const float* __restrict__ hsrc = (tid < 128) ? h2F : h2B;
        const int d = tid & 127;
        float acc = 0.f;
        for (int b = 0; b < 64; ++b)
            acc = fmaf(sc[b], hsrc[(p * 64 + b) * 128 + d], acc);
        femb[tid] = acc;
    }
    __syncthreads();

    const float fv = femb[tid];
    #pragma unroll
    for (int c = 0; c < 10; ++c) {
        float s = fv * wf[c * 256 + tid];
        s += __shfl_xor(s, 1);
        s += __shfl_xor(s, 2);
        s += __shfl_xor(s, 4);
        s += __shfl_xor(s, 8);
        s += __shfl_xor(s, 16);
        s += __shfl_xor(s, 32);
        if ((tid & 63) == 0) red[(c << 2) | (tid >> 6)] = s;
        __syncthreads();
        if (tid == 0)
            outp[p * 10 + c] = bfv[c] + red[c << 2] + red[(c << 2) | 1] +
                               red[(c << 2) | 2] + red[(c << 2) | 3];
        __syncthreads();
    }
}

// ---------------------------------------------------------------------------
extern "C" void kernel_launch(void* const* d_in, const int* in_sizes, int n_in,
                              void* d_out, int out_size, void* d_ws,
                              size_t ws_size, hipStream_t stream) {
    const int* flow = (const int*)d_in[0];
    const float* emb = (const float*)d_in[1];
    const float* byte_wih_f = (const float*)d_in[2];
    const float* byte_whh_f = (const float*)d_in[3];
    const float* byte_bih_f = (const float*)d_in[4];
    const float* byte_bhh_f = (const float*)d_in[5];
    const float* byte_wih_b = (const float*)d_in[6];
    const float* byte_whh_b = (const float*)d_in[7];
    const float* byte_bih_b = (const float*)d_in[8];
    const float* byte_bhh_b = (const float*)d_in[9];
    const float* pkt_wih_f = (const float*)d_in[10];
    const float* pkt_whh_f = (const float*)d_in[11];
    const float* pkt_bih_f = (const float*)d_in[12];
    const float* pkt_bhh_f = (const float*)d_in[13];
    const float* pkt_wih_b = (const float*)d_in[14];
    const float* pkt_whh_b = (const float*)d_in[15];
    const float* pkt_bih_b = (const float*)d_in[16];
    const float* pkt_bhh_b = (const float*)d_in[17];
    const float* ba_w1 = (const float*)d_in[18];
    const float* ba_b1 = (const float*)d_in[19];
    const float* ba_w2 = (const float*)d_in[20];
    const float* ba_b2 = (const float*)d_in[21];
    const float* pa_w1 = (const float*)d_in[22];
    const float* pa_b1 = (const float*)d_in[23];
    const float* pa_w2 = (const float*)d_in[24];
    const float* pa_b2 = (const float*)d_in[25];
    const float* wf = (const float*)d_in[26];
    const float* bf = (const float*)d_in[27];

    char* base = (char*)d_ws;
    size_t off = 0;
    auto allocf = [&](size_t nf) -> float* {
        float* p = (float*)(base + off);
        off += nf * sizeof(float);
        return p;
    };
    auto alloch = [&](size_t nh) -> __half* {
        off = (off + 255) & ~(size_t)255;
        __half* p = (__half*)(base + off);
        off += nh * sizeof(__half);
        return p;
    };
    float* wihTpF = allocf(256 * 384);
    float* wihTpB = allocf(256 * 384);
    float* attn = allocf(262144);
    float* pe = allocf(2048 * 256);
    float4* tab4F = (float4*)allocf(256 * 128 * 4);
    float4* tab4B = (float4*)allocf(256 * 128 * 4);
    float4* xg4F = (float4*)allocf((size_t)2048 * 128 * 4);
    float4* xg4B = (float4*)allocf((size_t)2048 * 128 * 4);
    float* h2F = allocf(32 * 64 * 128);
    float* h2B = allocf(32 * 64 * 128);
    float* scores2 = allocf(2048);
    __half* w1h = alloch(128 * 256);
    __half* hF = alloch((size_t)128 * 2048 * 128);
    __half* hB = alloch((size_t)128 * 2048 * 128);
    if (off > ws_size) return;  // diagnostic: leaves d_out poisoned
    (void)in_sizes; (void)n_in; (void)out_size;

    k_tables_w1<<<832, 384, 0, stream>>>(emb, byte_wih_f, byte_bih_f,
                                         byte_bhh_f, byte_wih_b, byte_bih_b,
                                         byte_bhh_b, tab4F, tab4B, ba_w1,
                                         (f16*)w1h, pkt_wih_f, pkt_wih_b,
                                         wihTpF, wihTpB);

    k_byte_gru<<<256, 512, 0, stream>>>(flow, tab4F, tab4B, byte_whh_f,
                                        byte_whh_b, byte_bhh_f, byte_bhh_b, hF,
                                        hB);

    k_scores_attn<<<1024, 256, 0, stream>>>(hF, hB, (const f16*)w1h, ba_b1,
                                            ba_w2, ba_b2, attn);
    k_packet_emb<<<1024, 256, 0, stream>>>(hF, hB, attn, pe);

    k_pkt_xg<<<dim3(256, 2), 384, 0, stream>>>(pe, wihTpF, pkt_bih_f,
                                               pkt_bhh_f, wihTpB, pkt_bih_b,
                                               pkt_bhh_b, xg4F, xg4B);
    k_pkt_gru<<<32, 512, 0, stream>>>(xg4F, xg4B, pkt_whh_f, pkt_whh_b,
                                      pkt_bhh_f, pkt_bhh_b, h2F, h2B);
    k_scores2<<<2048, 128, 0, stream>>>(h2F, h2B, pa_w1, pa_b1, pa_w2, pa_b2,
                                        scores2);
    k_final3<<<32, 256, 0, stream>>>(h2F, h2B, scores2, wf, bf, (float*)d_out);
}